// Round 7
// baseline (432.837 us; speedup 1.0000x reference)
//
#include <hip/hip_runtime.h>
#include <hip/hip_bf16.h>

// 3-layer SplineConv (3x3, degree 2, open spline).
// Round 7: y/msg arrays eliminated. Per layer:
//   root_mfma: agg[n] = X@root + bias (MFMA); also writes xbf[n] = bf16(X row)
//   edge_mfma: edges dst-sorted (CSR). Block owns 32 nodes + their edge range.
//     Wave takes 16 edges: gathers 16 xbf rows (A-frags), scales A by the
//     edge's spline coef per k (9 iters), MFMAs against W panel in LDS,
//     LDS-atomicAdds C rows (=edges) into a [32 node][32 ch] fp32 tile,
//     final: agg += tile, relu, store.  msg = (B_k .* X) @ W_k summed -- the
//     x@W redundancy per edge is free (MFMA), the gather is 128B/edge not 576B.
// Prep: single counting sort by dst -> erec {src,dst,p0,p1} float4 + CSR.

typedef __attribute__((ext_vector_type(8))) short short8;
typedef __attribute__((ext_vector_type(4))) float f32x4;

__device__ __forceinline__ float bf2f(unsigned short u) {
    union { unsigned u; float f; } x; x.u = ((unsigned)u) << 16; return x.f;
}
__device__ __forceinline__ unsigned short f2bf(float f) {
    union { float f; unsigned u; } x; x.f = f;
    unsigned r = x.u + 0x7fffu + ((x.u >> 16) & 1u);   // RNE
    return (unsigned short)(r >> 16);
}
__device__ __forceinline__ short8 cvt8(const float* p) {
    float4 a = *(const float4*)p;
    float4 b = *(const float4*)(p + 4);
    short8 r;
    r[0] = (short)f2bf(a.x); r[1] = (short)f2bf(a.y);
    r[2] = (short)f2bf(a.z); r[3] = (short)f2bf(a.w);
    r[4] = (short)f2bf(b.x); r[5] = (short)f2bf(b.y);
    r[6] = (short)f2bf(b.z); r[7] = (short)f2bf(b.w);
    return r;
}

// MODE 0: X = Xa [N,64];  MODE 1: X = [Xa[N,32]|Xb[N,32]];  MODE 2: X = Xa [N,32]
template<int MODE>
__global__ __launch_bounds__(256)
void root_mfma(const float* __restrict__ Xa, const float* __restrict__ Xb,
               const unsigned short* __restrict__ Wt,   // [320][CIN] bf16
               const float* __restrict__ bias,
               unsigned short* __restrict__ xbf, float* __restrict__ agg, int N)
{
    constexpr int CIN = (MODE == 2) ? 32 : 64;
    const int t    = threadIdx.x;
    const int wv   = t >> 6;
    const int lane = t & 63;
    const int lc   = lane & 15;
    const int q    = lane >> 4;
    const int base = blockIdx.x * 64 + wv * 16;

    int na = base + lc;
    if (na >= N) na = N - 1;
    short8 a0, a1;
    if (MODE == 0) {
        const float* p = Xa + (size_t)na * 64 + q * 8;
        a0 = cvt8(p);
        a1 = cvt8(p + 32);
    } else if (MODE == 1) {
        a0 = cvt8(Xa + (size_t)na * 32 + q * 8);
        a1 = cvt8(Xb + (size_t)na * 32 + q * 8);
    } else {
        a0 = cvt8(Xa + (size_t)na * 32 + q * 8);
    }

    // persist bf16 X rows for the edge kernel (clamped lanes rewrite same data)
    *(short8*)(xbf + (size_t)na * CIN + q * 8) = a0;
    if (MODE != 2) *(short8*)(xbf + (size_t)na * CIN + 32 + q * 8) = a1;

    f32x4 acc[2];
    acc[0] = (f32x4){0.f, 0.f, 0.f, 0.f};
    acc[1] = (f32x4){0.f, 0.f, 0.f, 0.f};
    #pragma unroll
    for (int ct = 0; ct < 2; ++ct) {
        const unsigned short* wp = Wt + ((size_t)(288 + ct * 16 + lc)) * CIN + q * 8;
        acc[ct] = __builtin_amdgcn_mfma_f32_16x16x32_bf16(a0, *(const short8*)wp, acc[ct], 0, 0, 0);
        if (MODE != 2)
            acc[ct] = __builtin_amdgcn_mfma_f32_16x16x32_bf16(a1, *(const short8*)(wp + 32), acc[ct], 0, 0, 0);
    }

    #pragma unroll
    for (int ct = 0; ct < 2; ++ct) {
        float bv = bias[ct * 16 + lc];
        #pragma unroll
        for (int r = 0; r < 4; ++r) {
            int n = base + q * 4 + r;
            if (n < N) agg[(size_t)n * 32 + ct * 16 + lc] = acc[ct][r] + bv;
        }
    }
}

// edge kernel: block = 32 dst nodes + their contiguous dst-sorted edge range
template<int CIN>
__global__ __launch_bounds__(256)
void edge_mfma(const unsigned short* __restrict__ xbf,
               const unsigned short* __restrict__ Wt,   // rows 0..287 staged to LDS
               const int* __restrict__ rowend, const float4* __restrict__ erec,
               float* __restrict__ agg, int N)
{
    constexpr int HK = CIN / 32;             // K-halves (2 for CIN=64, 1 for CIN=32)
    __shared__ unsigned short sW[288 * 72];  // row stride 72 shorts (36 dw, 16B-aligned, 2-way banks)
    __shared__ float sTile[32][33];
    __shared__ int sDst[4][16];

    const int t    = threadIdx.x;
    const int wv   = t >> 6;
    const int lane = t & 63;
    const int lc   = lane & 15;
    const int q    = lane >> 4;
    const int n0   = blockIdx.x * 32;

    // stage W panel (int-granule, coalesced)
    const int IPR = CIN / 2;                 // ints per source row
    const int* wsrc = (const int*)Wt;
    int* wdst = (int*)sW;
    for (int i = t; i < 288 * IPR; i += 256) {
        int r = i / IPR, k2 = i % IPR;
        wdst[r * 36 + k2] = wsrc[i];
    }
    for (int i = t; i < 32 * 33; i += 256) ((float*)sTile)[i] = 0.f;
    __syncthreads();

    const int E0 = (n0 == 0) ? 0 : rowend[n0 - 1];
    const int lastn = min(n0 + 32, N) - 1;
    const int E1 = rowend[lastn];

    for (int eb = E0 + wv * 16; eb < E1; eb += 64) {
        const int ee = eb + lc;
        const bool valid = ee < E1;
        const float4 rr = erec[valid ? ee : E0];
        const int src = __float_as_int(rr.x);
        const int dst = __float_as_int(rr.y);
        const float p0 = rr.z, p1 = rr.w;

        float qb[3] = {0.5f * (1.f - p0) * (1.f - p0), -p0 * p0 + p0 + 0.5f, 0.5f * p0 * p0};
        float qa[3] = {0.5f * (1.f - p1) * (1.f - p1), -p1 * p1 + p1 + 0.5f, 0.5f * p1 * p1};
        if (!valid) { qa[0] = 0.f; qa[1] = 0.f; qa[2] = 0.f; }
        if (q == 0) sDst[wv][lc] = valid ? (dst - n0) : 0;

        // gather bf16 X row chunk(s): 16 B per K-half
        const unsigned short* xp = xbf + (size_t)src * CIN + q * 8;
        short8 x0 = *(const short8*)xp;
        short8 x1;
        if (HK == 2) x1 = *(const short8*)(xp + 32);
        float xr[8 * HK];
        #pragma unroll
        for (int j = 0; j < 8; ++j) xr[j] = bf2f((unsigned short)x0[j]);
        if (HK == 2) {
            #pragma unroll
            for (int j = 0; j < 8; ++j) xr[8 + j] = bf2f((unsigned short)x1[j]);
        }

        f32x4 acc[2];
        acc[0] = (f32x4){0.f, 0.f, 0.f, 0.f};
        acc[1] = (f32x4){0.f, 0.f, 0.f, 0.f};

        #pragma unroll
        for (int kk = 0; kk < 9; ++kk) {
            const float coef = qa[kk / 3] * qb[kk % 3];
            union { short8 v; __hip_bfloat162 h[4]; } a0s, a1s;
            #pragma unroll
            for (int j = 0; j < 4; ++j)
                a0s.h[j] = __float22bfloat162_rn(float2{coef * xr[2 * j], coef * xr[2 * j + 1]});
            if (HK == 2) {
                #pragma unroll
                for (int j = 0; j < 4; ++j)
                    a1s.h[j] = __float22bfloat162_rn(float2{coef * xr[8 + 2 * j], coef * xr[9 + 2 * j]});
            }
            #pragma unroll
            for (int ct = 0; ct < 2; ++ct) {
                const unsigned short* wp = sW + (kk * 32 + ct * 16 + lc) * 72 + q * 8;
                acc[ct] = __builtin_amdgcn_mfma_f32_16x16x32_bf16(a0s.v, *(const short8*)wp, acc[ct], 0, 0, 0);
                if (HK == 2)
                    acc[ct] = __builtin_amdgcn_mfma_f32_16x16x32_bf16(a1s.v, *(const short8*)(wp + 32), acc[ct], 0, 0, 0);
            }
        }

        int dl[4];
        #pragma unroll
        for (int r = 0; r < 4; ++r) dl[r] = sDst[wv][q * 4 + r];
        #pragma unroll
        for (int ct = 0; ct < 2; ++ct)
            #pragma unroll
            for (int r = 0; r < 4; ++r)
                atomicAdd(&sTile[dl[r]][ct * 16 + lc], acc[ct][r]);
    }
    __syncthreads();

    for (int i = t; i < 32 * 32; i += 256) {
        int nl = i >> 5, c = i & 31, n = n0 + nl;
        if (n < N) {
            float v = agg[(size_t)n * 32 + c] + sTile[nl][c];
            agg[(size_t)n * 32 + c] = fmaxf(v, 0.f);
        }
    }
}

// build Wt[320][CIN] bf16 from W[9,CIN,32] f32 and root[CIN,32] f32
template<int CIN>
__global__ __launch_bounds__(256)
void build_wt_kernel(const float* __restrict__ W, const float* __restrict__ root,
                     unsigned short* __restrict__ Wt)
{
    int idx = blockIdx.x * 256 + threadIdx.x;
    if (idx >= 320 * CIN) return;
    int col = idx / CIN;
    int k   = idx % CIN;
    float v = (col < 288) ? W[((size_t)(col >> 5) * CIN + k) * 32 + (col & 31)]
                          : root[(size_t)k * 32 + (col - 288)];
    Wt[idx] = f2bf(v);
}

// ---------- prep: counting sort by dst ----------

__global__ __launch_bounds__(1024)
void zero_kernel(int* __restrict__ p, int n)
{
    int i = blockIdx.x * 1024 + threadIdx.x;
    if (i < n) p[i] = 0;
}

__global__ __launch_bounds__(256)
void count_kernel(const int* __restrict__ ei, int* __restrict__ hist, int E)
{
    int e = blockIdx.x * 256 + threadIdx.x;
    if (e < E) atomicAdd(&hist[ei[E + e]], 1);   // dst
}

__global__ __launch_bounds__(1024)
void scan1_kernel(int* __restrict__ hist, int* __restrict__ bsum, int n)
{
    __shared__ int s[1024];
    int tid = threadIdx.x;
    int i = blockIdx.x * 1024 + tid;
    int v = (i < n) ? hist[i] : 0;
    s[tid] = v;
    __syncthreads();
    for (int off = 1; off < 1024; off <<= 1) {
        int add = (tid >= off) ? s[tid - off] : 0;
        __syncthreads();
        s[tid] += add;
        __syncthreads();
    }
    if (i < n) hist[i] = s[tid] - v;
    if (tid == 1023) bsum[blockIdx.x] = s[1023];
}

__global__ __launch_bounds__(256)
void scan2_kernel(int* __restrict__ bsum, int nb)
{
    __shared__ int s[256];
    int tid = threadIdx.x;
    int v = (tid < nb) ? bsum[tid] : 0;
    s[tid] = v;
    __syncthreads();
    for (int off = 1; off < 256; off <<= 1) {
        int add = (tid >= off) ? s[tid - off] : 0;
        __syncthreads();
        s[tid] += add;
        __syncthreads();
    }
    if (tid < nb) bsum[tid] = s[tid] - v;
}

__global__ __launch_bounds__(1024)
void scan3_kernel(int* __restrict__ hist, const int* __restrict__ bsum, int n)
{
    int i = blockIdx.x * 1024 + threadIdx.x;
    if (i < n) hist[i] += bsum[blockIdx.x];
}

__global__ __launch_bounds__(256)
void scatter_kernel(const int* __restrict__ ei, const float* __restrict__ pseudo,
                    int* __restrict__ start, float4* __restrict__ erec, int E)
{
    int e = blockIdx.x * 256 + threadIdx.x;
    if (e >= E) return;
    int sv = ei[e];
    int dv = ei[E + e];
    float p0 = pseudo[2 * (size_t)e];
    float p1 = pseudo[2 * (size_t)e + 1];
    int ps = atomicAdd(&start[dv], 1);
    float4 r;
    r.x = __int_as_float(sv);
    r.y = __int_as_float(dv);
    r.z = p0;
    r.w = p1;
    erec[ps] = r;
}

extern "C" void kernel_launch(void* const* d_in, const int* in_sizes, int n_in,
                              void* d_out, int out_size, void* d_ws, size_t ws_size,
                              hipStream_t stream) {
    const float* x      = (const float*)d_in[0];
    const int*   ei     = (const int*)  d_in[1];
    const float* pseudo = (const float*)d_in[2];
    const float* skip   = (const float*)d_in[3];
    const float* W1     = (const float*)d_in[4];
    const float* root1  = (const float*)d_in[5];
    const float* b1     = (const float*)d_in[6];
    const float* W2     = (const float*)d_in[7];
    const float* root2  = (const float*)d_in[8];
    const float* b2     = (const float*)d_in[9];

    const int N = in_sizes[0] / 64;
    const int E = in_sizes[1] / 2;
    float* out = (float*)d_out;

    // ws (~26 MB): erec[E f4] xbf[N*64 bf16] aggA[N*32 f32] aggB[N*32 f32]
    //              start[N] bsum[256] Wt1[320*64] Wt2[320*32]
    float4* erec = (float4*)d_ws;
    unsigned short* xbf = (unsigned short*)(erec + E);
    float* aggA = (float*)(xbf + (size_t)N * 64);
    float* aggB = aggA + (size_t)N * 32;
    int*   start = (int*)(aggB + (size_t)N * 32);
    int*   bsum  = start + N;
    unsigned short* Wt1 = (unsigned short*)(bsum + 256);
    unsigned short* Wt2 = Wt1 + 320 * 64;

    const dim3 blk(256);
    const int rb   = (N + 63) / 64;
    const int ebk  = (N + 31) / 32;
    const int e256 = (E + 255) / 256;
    const int n1k  = (N + 1023) / 1024;
    int* rowend = start;   // after scatter: dst CSR end positions

    // ---- prep ----
    zero_kernel<<<n1k, 1024, 0, stream>>>(start, N);
    count_kernel<<<e256, blk, 0, stream>>>(ei, start, E);
    build_wt_kernel<64><<<(320 * 64 + 255) / 256, blk, 0, stream>>>(W1, root1, Wt1);
    build_wt_kernel<32><<<(320 * 32 + 255) / 256, blk, 0, stream>>>(W2, root2, Wt2);
    scan1_kernel<<<n1k, 1024, 0, stream>>>(start, bsum, N);
    scan2_kernel<<<1, 256, 0, stream>>>(bsum, n1k);
    scan3_kernel<<<n1k, 1024, 0, stream>>>(start, bsum, N);
    scatter_kernel<<<e256, blk, 0, stream>>>(ei, pseudo, start, erec, E);

    // ---- Layer 1 ----
    root_mfma<0><<<rb, blk, 0, stream>>>(x, nullptr, Wt1, b1, xbf, aggA, N);
    edge_mfma<64><<<ebk, blk, 0, stream>>>(xbf, Wt1, rowend, erec, aggA, N);   // h1
    // ---- Layer 2: X = concat(h1, skip) ----
    root_mfma<1><<<rb, blk, 0, stream>>>(aggA, skip, Wt1, b1, xbf, aggB, N);
    edge_mfma<64><<<ebk, blk, 0, stream>>>(xbf, Wt1, rowend, erec, aggB, N);   // h2
    // ---- Layer 3 -> d_out ----
    root_mfma<2><<<rb, blk, 0, stream>>>(aggB, nullptr, Wt2, b2, xbf, out, N);
    edge_mfma<32><<<ebk, blk, 0, stream>>>(xbf, Wt2, rowend, erec, out, N);    // relu fused
}

// Round 8
// 304.227 us; speedup vs baseline: 1.4227x; 1.4227x over previous
//
#include <hip/hip_runtime.h>
#include <hip/hip_bf16.h>

// 3-layer SplineConv (3x3, degree 2, open spline). Atomic-free per-layer path
// (round-6 structure, round-8 vectorization).
// Prep: dual counting sort (src & dst) via one 2N-wide scan; packed float4
//   edge record {src, dpos, p0, p1} at the src-sorted slot.
// Per layer:
//   transform_mfma: C[64 nodes][320] = X @ [W0..W8|root] via 16x16x32 bf16
//     MFMA; cols 0..287 -> y bf16, cols 288..319 -> agg = root-term + bias.
//   msg: 4 lanes/edge, uint4 (8ch) y loads: m = sum_{a,b} qa qb y[src],
//     bf16x8 store to dst-sorted slot (no atomics).
//   gather: 4 lanes/node, uint4 msg loads; agg += contiguous rows; relu.

typedef __attribute__((ext_vector_type(8))) short short8;
typedef __attribute__((ext_vector_type(4))) float f32x4;

__device__ __forceinline__ float bf2f(unsigned short u) {
    union { unsigned u; float f; } x; x.u = ((unsigned)u) << 16; return x.f;
}
__device__ __forceinline__ float blo(unsigned u) {
    union { unsigned u; float f; } x; x.u = u << 16; return x.f;
}
__device__ __forceinline__ float bhi(unsigned u) {
    union { unsigned u; float f; } x; x.u = u & 0xffff0000u; return x.f;
}
__device__ __forceinline__ unsigned short f2bf(float f) {
    union { float f; unsigned u; } x; x.f = f;
    unsigned r = x.u + 0x7fffu + ((x.u >> 16) & 1u);   // RNE
    return (unsigned short)(r >> 16);
}
__device__ __forceinline__ short8 cvt8(const float* p) {
    float4 a = *(const float4*)p;
    float4 b = *(const float4*)(p + 4);
    short8 r;
    r[0] = (short)f2bf(a.x); r[1] = (short)f2bf(a.y);
    r[2] = (short)f2bf(a.z); r[3] = (short)f2bf(a.w);
    r[4] = (short)f2bf(b.x); r[5] = (short)f2bf(b.y);
    r[6] = (short)f2bf(b.z); r[7] = (short)f2bf(b.w);
    return r;
}

// MODE 0: X = Xa [N,64];  MODE 1: X = [Xa[N,32]|Xb[N,32]];  MODE 2: X = Xa [N,32]
template<int MODE>
__global__ __launch_bounds__(256)
void transform_mfma(const float* __restrict__ Xa, const float* __restrict__ Xb,
                    const unsigned short* __restrict__ Wt,  // [320][CIN] bf16
                    const float* __restrict__ bias,
                    unsigned short* __restrict__ y, float* __restrict__ agg, int N)
{
    const int CIN = (MODE == 2) ? 32 : 64;
    const int t    = threadIdx.x;
    const int wv   = t >> 6;
    const int lane = t & 63;
    const int lc   = lane & 15;
    const int q    = lane >> 4;
    const int base = blockIdx.x * 64 + wv * 16;

    int na = base + lc;
    if (na >= N) na = N - 1;
    short8 a0, a1;
    if (MODE == 0) {
        const float* p = Xa + (size_t)na * 64 + q * 8;
        a0 = cvt8(p);
        a1 = cvt8(p + 32);
    } else if (MODE == 1) {
        a0 = cvt8(Xa + (size_t)na * 32 + q * 8);
        a1 = cvt8(Xb + (size_t)na * 32 + q * 8);
    } else {
        a0 = cvt8(Xa + (size_t)na * 32 + q * 8);
    }

    f32x4 acc[20];
    #pragma unroll
    for (int nt = 0; nt < 20; ++nt) acc[nt] = (f32x4){0.f, 0.f, 0.f, 0.f};

    #pragma unroll
    for (int nt = 0; nt < 20; ++nt) {
        const unsigned short* wp = Wt + ((size_t)(nt * 16 + lc)) * CIN + q * 8;
        acc[nt] = __builtin_amdgcn_mfma_f32_16x16x32_bf16(a0, *(const short8*)wp, acc[nt], 0, 0, 0);
        if (MODE != 2)
            acc[nt] = __builtin_amdgcn_mfma_f32_16x16x32_bf16(a1, *(const short8*)(wp + 32), acc[nt], 0, 0, 0);
    }

    #pragma unroll
    for (int nt = 0; nt < 20; ++nt) {
        #pragma unroll
        for (int r = 0; r < 4; ++r) {
            int n = base + q * 4 + r;
            if (n >= N) continue;
            if (nt < 18) {
                y[(size_t)n * 288 + nt * 16 + lc] = f2bf(acc[nt][r]);
            } else {
                int c = (nt - 18) * 16 + lc;
                agg[(size_t)n * 32 + c] = acc[nt][r] + bias[c];
            }
        }
    }
}

// build Wt[320][CIN] bf16 from W[9,CIN,32] f32 and root[CIN,32] f32
template<int CIN>
__global__ __launch_bounds__(256)
void build_wt_kernel(const float* __restrict__ W, const float* __restrict__ root,
                     unsigned short* __restrict__ Wt)
{
    int idx = blockIdx.x * 256 + threadIdx.x;
    if (idx >= 320 * CIN) return;
    int col = idx / CIN;
    int k   = idx % CIN;
    float v = (col < 288) ? W[((size_t)(col >> 5) * CIN + k) * 32 + (col & 31)]
                          : root[(size_t)k * 32 + (col - 288)];
    Wt[idx] = f2bf(v);
}

// msg: 4 lanes/edge, 8 channels/lane via uint4 (16B) loads
__global__ __launch_bounds__(256)
void msg_kernel(const float4* __restrict__ erec,
                const uint4* __restrict__ y4,    // [N][36] uint4 (row = 576B)
                uint4* __restrict__ msg4, int E) // [E][4]  uint4 (row = 64B)
{
    const int t = threadIdx.x;
    const int e = blockIdx.x * 64 + (t >> 2);
    if (e >= E) return;
    const int l = t & 3;

    const float4 r = erec[e];
    const int src = __float_as_int(r.x);
    const int dp  = __float_as_int(r.y);
    const float p0 = r.z, p1 = r.w;

    const float qb[3] = {0.5f * (1.f - p0) * (1.f - p0), -p0 * p0 + p0 + 0.5f, 0.5f * p0 * p0};
    const float qa[3] = {0.5f * (1.f - p1) * (1.f - p1), -p1 * p1 + p1 + 0.5f, 0.5f * p1 * p1};

    const uint4* yb = y4 + (size_t)src * 36 + l;
    float s[8] = {0.f, 0.f, 0.f, 0.f, 0.f, 0.f, 0.f, 0.f};
    #pragma unroll
    for (int a = 0; a < 3; ++a) {
        float z[8] = {0.f, 0.f, 0.f, 0.f, 0.f, 0.f, 0.f, 0.f};
        #pragma unroll
        for (int b = 0; b < 3; ++b) {
            uint4 v = yb[(a * 3 + b) * 4];
            const float cw = qb[b];
            z[0] = fmaf(cw, blo(v.x), z[0]); z[1] = fmaf(cw, bhi(v.x), z[1]);
            z[2] = fmaf(cw, blo(v.y), z[2]); z[3] = fmaf(cw, bhi(v.y), z[3]);
            z[4] = fmaf(cw, blo(v.z), z[4]); z[5] = fmaf(cw, bhi(v.z), z[5]);
            z[6] = fmaf(cw, blo(v.w), z[6]); z[7] = fmaf(cw, bhi(v.w), z[7]);
        }
        #pragma unroll
        for (int j = 0; j < 8; ++j) s[j] = fmaf(qa[a], z[j], s[j]);
    }

    union { uint4 u; __hip_bfloat162 h[4]; } o;
    #pragma unroll
    for (int j = 0; j < 4; ++j)
        o.h[j] = __float22bfloat162_rn(float2{s[2 * j], s[2 * j + 1]});
    msg4[(size_t)dp * 4 + l] = o.u;
}

// gather: 4 lanes/node, uint4 msg loads; relu fused; in-place on agg
__global__ __launch_bounds__(256)
void gather_kernel(const int* __restrict__ rowend_d,  // values carry +E offset
                   const uint4* __restrict__ msg4,
                   float* __restrict__ agg, int N, int E)
{
    const int t = threadIdx.x;
    const int n = blockIdx.x * 64 + (t >> 2);
    if (n >= N) return;
    const int l = t & 3;

    const int e0 = ((n == 0) ? E : rowend_d[n - 1]) - E;
    const int e1 = rowend_d[n] - E;

    float4* ap = (float4*)(agg + (size_t)n * 32 + l * 8);
    float4 A = ap[0], B = ap[1];
    const uint4* mp = msg4 + l;
    for (int e = e0; e < e1; ++e) {
        uint4 v = mp[(size_t)e * 4];
        A.x += blo(v.x); A.y += bhi(v.x); A.z += blo(v.y); A.w += bhi(v.y);
        B.x += blo(v.z); B.y += bhi(v.z); B.z += blo(v.w); B.w += bhi(v.w);
    }
    A.x = fmaxf(A.x, 0.f); A.y = fmaxf(A.y, 0.f); A.z = fmaxf(A.z, 0.f); A.w = fmaxf(A.w, 0.f);
    B.x = fmaxf(B.x, 0.f); B.y = fmaxf(B.y, 0.f); B.z = fmaxf(B.z, 0.f); B.w = fmaxf(B.w, 0.f);
    ap[0] = A; ap[1] = B;
}

// ---------- prep: dual counting sort (src & dst), one 2N-wide scan ----------

__global__ __launch_bounds__(1024)
void zero_kernel(int* __restrict__ p, int n)
{
    int i = blockIdx.x * 1024 + threadIdx.x;
    if (i < n) p[i] = 0;
}

__global__ __launch_bounds__(256)
void count_both_kernel(const int* __restrict__ ei, int* __restrict__ hist, int N, int E)
{
    int e = blockIdx.x * 256 + threadIdx.x;
    if (e >= E) return;
    atomicAdd(&hist[ei[e]], 1);
    atomicAdd(&hist[N + ei[E + e]], 1);
}

__global__ __launch_bounds__(1024)
void scan1_kernel(int* __restrict__ hist, int* __restrict__ bsum, int n)
{
    __shared__ int s[1024];
    int tid = threadIdx.x;
    int i = blockIdx.x * 1024 + tid;
    int v = (i < n) ? hist[i] : 0;
    s[tid] = v;
    __syncthreads();
    for (int off = 1; off < 1024; off <<= 1) {
        int add = (tid >= off) ? s[tid - off] : 0;
        __syncthreads();
        s[tid] += add;
        __syncthreads();
    }
    if (i < n) hist[i] = s[tid] - v;
    if (tid == 1023) bsum[blockIdx.x] = s[1023];
}

__global__ __launch_bounds__(256)
void scan2_kernel(int* __restrict__ bsum, int nb)
{
    __shared__ int s[256];
    int tid = threadIdx.x;
    int v = (tid < nb) ? bsum[tid] : 0;
    s[tid] = v;
    __syncthreads();
    for (int off = 1; off < 256; off <<= 1) {
        int add = (tid >= off) ? s[tid - off] : 0;
        __syncthreads();
        s[tid] += add;
        __syncthreads();
    }
    if (tid < nb) bsum[tid] = s[tid] - v;
}

__global__ __launch_bounds__(1024)
void scan3_kernel(int* __restrict__ hist, const int* __restrict__ bsum, int n)
{
    int i = blockIdx.x * 1024 + threadIdx.x;
    if (i < n) hist[i] += bsum[blockIdx.x];
}

__global__ __launch_bounds__(256)
void scatter_both_kernel(const int* __restrict__ ei, const float* __restrict__ pseudo,
                         int* __restrict__ start,   // [0,N)=src cursors, [N,2N)=dst cursors(+E)
                         float4* __restrict__ erec, int N, int E)
{
    int e = blockIdx.x * 256 + threadIdx.x;
    if (e >= E) return;
    int sv = ei[e];
    int dv = ei[E + e];
    float p0 = pseudo[2 * (size_t)e];
    float p1 = pseudo[2 * (size_t)e + 1];
    int ps = atomicAdd(&start[sv], 1);
    int pd = atomicAdd(&start[N + dv], 1) - E;
    float4 r;
    r.x = __int_as_float(sv);
    r.y = __int_as_float(pd);
    r.z = p0;
    r.w = p1;
    erec[ps] = r;
}

extern "C" void kernel_launch(void* const* d_in, const int* in_sizes, int n_in,
                              void* d_out, int out_size, void* d_ws, size_t ws_size,
                              hipStream_t stream) {
    const float* x      = (const float*)d_in[0];
    const int*   ei     = (const int*)  d_in[1];
    const float* pseudo = (const float*)d_in[2];
    const float* skip   = (const float*)d_in[3];
    const float* W1     = (const float*)d_in[4];
    const float* root1  = (const float*)d_in[5];
    const float* b1     = (const float*)d_in[6];
    const float* W2     = (const float*)d_in[7];
    const float* root2  = (const float*)d_in[8];
    const float* b2     = (const float*)d_in[9];

    const int N = in_sizes[0] / 64;
    const int E = in_sizes[1] / 2;
    float* out = (float*)d_out;

    // ws (~67.7 MB): y[N*288 bf16] msg[E*32 bf16] agg1[N*32 f32] erec[E f4]
    //                start[2N] bsum[256] Wt1[320*64 bf16] Wt2[320*32 bf16]
    unsigned short* y   = (unsigned short*)d_ws;
    unsigned short* msg = y + (size_t)N * 288;
    float*  agg1  = (float*)(msg + (size_t)E * 32);
    float4* erec  = (float4*)(agg1 + (size_t)N * 32);
    int*    start = (int*)(erec + E);
    int*    bsum  = start + 2 * N;
    unsigned short* Wt1 = (unsigned short*)(bsum + 256);
    unsigned short* Wt2 = Wt1 + 320 * 64;

    const dim3 blk(256);
    const int tb   = (N + 63) / 64;
    const int eb   = (E + 63) / 64;
    const int gb   = (N + 63) / 64;
    const int e256 = (E + 255) / 256;
    const int n2k  = (2 * N + 1023) / 1024;
    int* rowend_d = start + N;   // after scatter: dst CSR end positions (+E)

    // ---- prep ----
    zero_kernel<<<n2k, 1024, 0, stream>>>(start, 2 * N);
    count_both_kernel<<<e256, blk, 0, stream>>>(ei, start, N, E);
    build_wt_kernel<64><<<(320 * 64 + 255) / 256, blk, 0, stream>>>(W1, root1, Wt1);
    build_wt_kernel<32><<<(320 * 32 + 255) / 256, blk, 0, stream>>>(W2, root2, Wt2);
    scan1_kernel<<<n2k, 1024, 0, stream>>>(start, bsum, 2 * N);
    scan2_kernel<<<1, 256, 0, stream>>>(bsum, n2k);
    scan3_kernel<<<n2k, 1024, 0, stream>>>(start, bsum, 2 * N);
    scatter_both_kernel<<<e256, blk, 0, stream>>>(ei, pseudo, start, erec, N, E);

    // ---- Layer 1 ----
    transform_mfma<0><<<tb, blk, 0, stream>>>(x, nullptr, Wt1, b1, y, agg1, N);
    msg_kernel<<<eb, blk, 0, stream>>>(erec, (const uint4*)y, (uint4*)msg, E);
    gather_kernel<<<gb, blk, 0, stream>>>(rowend_d, (const uint4*)msg, agg1, N, E);   // h1
    // ---- Layer 2: X = concat(h1, skip) ----
    transform_mfma<1><<<tb, blk, 0, stream>>>(agg1, skip, Wt1, b1, y, agg1, N);
    msg_kernel<<<eb, blk, 0, stream>>>(erec, (const uint4*)y, (uint4*)msg, E);
    gather_kernel<<<gb, blk, 0, stream>>>(rowend_d, (const uint4*)msg, agg1, N, E);   // h2
    // ---- Layer 3 -> d_out ----
    transform_mfma<2><<<tb, blk, 0, stream>>>(agg1, nullptr, Wt2, b2, y, out, N);
    msg_kernel<<<eb, blk, 0, stream>>>(erec, (const uint4*)y, (uint4*)msg, E);
    gather_kernel<<<gb, blk, 0, stream>>>(rowend_d, (const uint4*)msg, out, N, E);    // relu fused
}

// Round 9
// 278.104 us; speedup vs baseline: 1.5564x; 1.0939x over previous
//
#include <hip/hip_runtime.h>
#include <hip/hip_bf16.h>

// 3-layer SplineConv (3x3, degree 2, open spline). Atomic-free per-layer path.
// Prep: dual counting sort (src & dst), one 2N-wide scan. Round 9: the rank of
//   each edge within its bin is captured in the COUNT pass (atomicAdd return),
//   so the scatter has NO atomics / no dependent latency chain:
//   ps = start[src]+rs, pd = start[N+dst]+rd-E; one packed float4 erec store.
// Per layer:
//   transform_mfma: C[64 nodes][320] = X @ [W0..W8|root] (16x16x32 bf16 MFMA);
//     cols 0..287 -> y bf16, cols 288..319 -> agg = root-term + bias (f32).
//   msg: 4 lanes/edge, uint4 (8ch) y loads; bf16x8 store to dst-sorted slot.
//   gather: 4 lanes/node, uint4 msg loads over contiguous segment; relu fused.

typedef __attribute__((ext_vector_type(8))) short short8;
typedef __attribute__((ext_vector_type(4))) float f32x4;

__device__ __forceinline__ float blo(unsigned u) {
    union { unsigned u; float f; } x; x.u = u << 16; return x.f;
}
__device__ __forceinline__ float bhi(unsigned u) {
    union { unsigned u; float f; } x; x.u = u & 0xffff0000u; return x.f;
}
__device__ __forceinline__ unsigned short f2bf(float f) {
    union { float f; unsigned u; } x; x.f = f;
    unsigned r = x.u + 0x7fffu + ((x.u >> 16) & 1u);   // RNE
    return (unsigned short)(r >> 16);
}
__device__ __forceinline__ short8 cvt8(const float* p) {
    float4 a = *(const float4*)p;
    float4 b = *(const float4*)(p + 4);
    short8 r;
    r[0] = (short)f2bf(a.x); r[1] = (short)f2bf(a.y);
    r[2] = (short)f2bf(a.z); r[3] = (short)f2bf(a.w);
    r[4] = (short)f2bf(b.x); r[5] = (short)f2bf(b.y);
    r[6] = (short)f2bf(b.z); r[7] = (short)f2bf(b.w);
    return r;
}

// MODE 0: X = Xa [N,64];  MODE 1: X = [Xa[N,32]|Xb[N,32]];  MODE 2: X = Xa [N,32]
template<int MODE>
__global__ __launch_bounds__(256)
void transform_mfma(const float* __restrict__ Xa, const float* __restrict__ Xb,
                    const unsigned short* __restrict__ Wt,  // [320][CIN] bf16
                    const float* __restrict__ bias,
                    unsigned short* __restrict__ y, float* __restrict__ agg, int N)
{
    const int CIN = (MODE == 2) ? 32 : 64;
    const int t    = threadIdx.x;
    const int wv   = t >> 6;
    const int lane = t & 63;
    const int lc   = lane & 15;
    const int q    = lane >> 4;
    const int base = blockIdx.x * 64 + wv * 16;

    int na = base + lc;
    if (na >= N) na = N - 1;
    short8 a0, a1;
    if (MODE == 0) {
        const float* p = Xa + (size_t)na * 64 + q * 8;
        a0 = cvt8(p);
        a1 = cvt8(p + 32);
    } else if (MODE == 1) {
        a0 = cvt8(Xa + (size_t)na * 32 + q * 8);
        a1 = cvt8(Xb + (size_t)na * 32 + q * 8);
    } else {
        a0 = cvt8(Xa + (size_t)na * 32 + q * 8);
    }

    f32x4 acc[20];
    #pragma unroll
    for (int nt = 0; nt < 20; ++nt) acc[nt] = (f32x4){0.f, 0.f, 0.f, 0.f};

    #pragma unroll
    for (int nt = 0; nt < 20; ++nt) {
        const unsigned short* wp = Wt + ((size_t)(nt * 16 + lc)) * CIN + q * 8;
        acc[nt] = __builtin_amdgcn_mfma_f32_16x16x32_bf16(a0, *(const short8*)wp, acc[nt], 0, 0, 0);
        if (MODE != 2)
            acc[nt] = __builtin_amdgcn_mfma_f32_16x16x32_bf16(a1, *(const short8*)(wp + 32), acc[nt], 0, 0, 0);
    }

    #pragma unroll
    for (int nt = 0; nt < 20; ++nt) {
        #pragma unroll
        for (int r = 0; r < 4; ++r) {
            int n = base + q * 4 + r;
            if (n >= N) continue;
            if (nt < 18) {
                y[(size_t)n * 288 + nt * 16 + lc] = f2bf(acc[nt][r]);
            } else {
                int c = (nt - 18) * 16 + lc;
                agg[(size_t)n * 32 + c] = acc[nt][r] + bias[c];
            }
        }
    }
}

// build Wt[320][CIN] bf16 from W[9,CIN,32] f32 and root[CIN,32] f32
template<int CIN>
__global__ __launch_bounds__(256)
void build_wt_kernel(const float* __restrict__ W, const float* __restrict__ root,
                     unsigned short* __restrict__ Wt)
{
    int idx = blockIdx.x * 256 + threadIdx.x;
    if (idx >= 320 * CIN) return;
    int col = idx / CIN;
    int k   = idx % CIN;
    float v = (col < 288) ? W[((size_t)(col >> 5) * CIN + k) * 32 + (col & 31)]
                          : root[(size_t)k * 32 + (col - 288)];
    Wt[idx] = f2bf(v);
}

// msg: 4 lanes/edge, 8 channels/lane via uint4 (16B) loads
__global__ __launch_bounds__(256)
void msg_kernel(const float4* __restrict__ erec,
                const uint4* __restrict__ y4,    // [N][36] uint4 (row = 576B)
                uint4* __restrict__ msg4, int E) // [E][4]  uint4 (row = 64B)
{
    const int t = threadIdx.x;
    const int e = blockIdx.x * 64 + (t >> 2);
    if (e >= E) return;
    const int l = t & 3;

    const float4 r = erec[e];
    const int src = __float_as_int(r.x);
    const int dp  = __float_as_int(r.y);
    const float p0 = r.z, p1 = r.w;

    const float qb[3] = {0.5f * (1.f - p0) * (1.f - p0), -p0 * p0 + p0 + 0.5f, 0.5f * p0 * p0};
    const float qa[3] = {0.5f * (1.f - p1) * (1.f - p1), -p1 * p1 + p1 + 0.5f, 0.5f * p1 * p1};

    const uint4* yb = y4 + (size_t)src * 36 + l;
    float s[8] = {0.f, 0.f, 0.f, 0.f, 0.f, 0.f, 0.f, 0.f};
    #pragma unroll
    for (int a = 0; a < 3; ++a) {
        float z[8] = {0.f, 0.f, 0.f, 0.f, 0.f, 0.f, 0.f, 0.f};
        #pragma unroll
        for (int b = 0; b < 3; ++b) {
            uint4 v = yb[(a * 3 + b) * 4];
            const float cw = qb[b];
            z[0] = fmaf(cw, blo(v.x), z[0]); z[1] = fmaf(cw, bhi(v.x), z[1]);
            z[2] = fmaf(cw, blo(v.y), z[2]); z[3] = fmaf(cw, bhi(v.y), z[3]);
            z[4] = fmaf(cw, blo(v.z), z[4]); z[5] = fmaf(cw, bhi(v.z), z[5]);
            z[6] = fmaf(cw, blo(v.w), z[6]); z[7] = fmaf(cw, bhi(v.w), z[7]);
        }
        #pragma unroll
        for (int j = 0; j < 8; ++j) s[j] = fmaf(qa[a], z[j], s[j]);
    }

    union { uint4 u; __hip_bfloat162 h[4]; } o;
    #pragma unroll
    for (int j = 0; j < 4; ++j)
        o.h[j] = __float22bfloat162_rn(float2{s[2 * j], s[2 * j + 1]});
    msg4[(size_t)dp * 4 + l] = o.u;
}

// gather: 4 lanes/node; segment = [dstart[n], dstart[n+1]) - E  (last end = E)
__global__ __launch_bounds__(256)
void gather_kernel(const int* __restrict__ dstart,  // exclusive starts, +E offset
                   const uint4* __restrict__ msg4,
                   float* __restrict__ agg, int N, int E)
{
    const int t = threadIdx.x;
    const int n = blockIdx.x * 64 + (t >> 2);
    if (n >= N) return;
    const int l = t & 3;

    const int e0 = dstart[n] - E;
    const int e1 = ((n + 1 < N) ? dstart[n + 1] : 2 * E) - E;

    float4* ap = (float4*)(agg + (size_t)n * 32 + l * 8);
    float4 A = ap[0], B = ap[1];
    const uint4* mp = msg4 + l;
    for (int e = e0; e < e1; ++e) {
        uint4 v = mp[(size_t)e * 4];
        A.x += blo(v.x); A.y += bhi(v.x); A.z += blo(v.y); A.w += bhi(v.y);
        B.x += blo(v.z); B.y += bhi(v.z); B.z += blo(v.w); B.w += bhi(v.w);
    }
    A.x = fmaxf(A.x, 0.f); A.y = fmaxf(A.y, 0.f); A.z = fmaxf(A.z, 0.f); A.w = fmaxf(A.w, 0.f);
    B.x = fmaxf(B.x, 0.f); B.y = fmaxf(B.y, 0.f); B.z = fmaxf(B.z, 0.f); B.w = fmaxf(B.w, 0.f);
    ap[0] = A; ap[1] = B;
}

// ---------- prep: dual counting sort (src & dst), one 2N-wide scan ----------

__global__ __launch_bounds__(1024)
void zero_kernel(int* __restrict__ p, int n)
{
    int i = blockIdx.x * 1024 + threadIdx.x;
    if (i < n) p[i] = 0;
}

// count both bins AND capture each edge's rank within its bin (free: same atomic)
__global__ __launch_bounds__(256)
void count_rank_kernel(const int* __restrict__ ei, int* __restrict__ hist,
                       uint2* __restrict__ rank, int N, int E)
{
    int e = blockIdx.x * 256 + threadIdx.x;
    if (e >= E) return;
    unsigned rs = atomicAdd(&hist[ei[e]], 1);
    unsigned rd = atomicAdd(&hist[N + ei[E + e]], 1);
    rank[e] = uint2{rs, rd};
}

__global__ __launch_bounds__(1024)
void scan1_kernel(int* __restrict__ hist, int* __restrict__ bsum, int n)
{
    __shared__ int s[1024];
    int tid = threadIdx.x;
    int i = blockIdx.x * 1024 + tid;
    int v = (i < n) ? hist[i] : 0;
    s[tid] = v;
    __syncthreads();
    for (int off = 1; off < 1024; off <<= 1) {
        int add = (tid >= off) ? s[tid - off] : 0;
        __syncthreads();
        s[tid] += add;
        __syncthreads();
    }
    if (i < n) hist[i] = s[tid] - v;
    if (tid == 1023) bsum[blockIdx.x] = s[1023];
}

__global__ __launch_bounds__(256)
void scan2_kernel(int* __restrict__ bsum, int nb)
{
    __shared__ int s[256];
    int tid = threadIdx.x;
    int v = (tid < nb) ? bsum[tid] : 0;
    s[tid] = v;
    __syncthreads();
    for (int off = 1; off < 256; off <<= 1) {
        int add = (tid >= off) ? s[tid - off] : 0;
        __syncthreads();
        s[tid] += add;
        __syncthreads();
    }
    if (tid < nb) bsum[tid] = s[tid] - v;
}

__global__ __launch_bounds__(1024)
void scan3_kernel(int* __restrict__ hist, const int* __restrict__ bsum, int n)
{
    int i = blockIdx.x * 1024 + threadIdx.x;
    if (i < n) hist[i] += bsum[blockIdx.x];
}

// no atomics: positions from exclusive starts + pre-captured ranks
__global__ __launch_bounds__(256)
void scatter_plain_kernel(const int* __restrict__ ei, const float* __restrict__ pseudo,
                          const int* __restrict__ start, const uint2* __restrict__ rank,
                          float4* __restrict__ erec, int N, int E)
{
    int e = blockIdx.x * 256 + threadIdx.x;
    if (e >= E) return;
    int sv = ei[e];
    int dv = ei[E + e];
    uint2 rk = rank[e];
    int ps = start[sv] + (int)rk.x;
    int pd = start[N + dv] + (int)rk.y - E;
    float4 r;
    r.x = __int_as_float(sv);
    r.y = __int_as_float(pd);
    r.z = pseudo[2 * (size_t)e];
    r.w = pseudo[2 * (size_t)e + 1];
    erec[ps] = r;
}

extern "C" void kernel_launch(void* const* d_in, const int* in_sizes, int n_in,
                              void* d_out, int out_size, void* d_ws, size_t ws_size,
                              hipStream_t stream) {
    const float* x      = (const float*)d_in[0];
    const int*   ei     = (const int*)  d_in[1];
    const float* pseudo = (const float*)d_in[2];
    const float* skip   = (const float*)d_in[3];
    const float* W1     = (const float*)d_in[4];
    const float* root1  = (const float*)d_in[5];
    const float* b1     = (const float*)d_in[6];
    const float* W2     = (const float*)d_in[7];
    const float* root2  = (const float*)d_in[8];
    const float* b2     = (const float*)d_in[9];

    const int N = in_sizes[0] / 64;
    const int E = in_sizes[1] / 2;
    float* out = (float*)d_out;

    // ws (~71 MB): y[N*288 bf16] msg[E*32 bf16] agg1[N*32 f32] erec[E f4]
    //              rank[E uint2] start[2N] bsum[256] Wt1[320*64] Wt2[320*32]
    unsigned short* y   = (unsigned short*)d_ws;
    unsigned short* msg = y + (size_t)N * 288;
    float*  agg1  = (float*)(msg + (size_t)E * 32);
    float4* erec  = (float4*)(agg1 + (size_t)N * 32);
    uint2*  rank  = (uint2*)(erec + E);
    int*    start = (int*)(rank + E);
    int*    bsum  = start + 2 * N;
    unsigned short* Wt1 = (unsigned short*)(bsum + 256);
    unsigned short* Wt2 = Wt1 + 320 * 64;

    const dim3 blk(256);
    const int tb   = (N + 63) / 64;
    const int eb   = (E + 63) / 64;
    const int gb   = (N + 63) / 64;
    const int e256 = (E + 255) / 256;
    const int n2k  = (2 * N + 1023) / 1024;
    int* dstart = start + N;   // exclusive starts of dst bins (+E offset)

    // ---- prep ----
    zero_kernel<<<n2k, 1024, 0, stream>>>(start, 2 * N);
    count_rank_kernel<<<e256, blk, 0, stream>>>(ei, start, rank, N, E);
    build_wt_kernel<64><<<(320 * 64 + 255) / 256, blk, 0, stream>>>(W1, root1, Wt1);
    build_wt_kernel<32><<<(320 * 32 + 255) / 256, blk, 0, stream>>>(W2, root2, Wt2);
    scan1_kernel<<<n2k, 1024, 0, stream>>>(start, bsum, 2 * N);
    scan2_kernel<<<1, 256, 0, stream>>>(bsum, n2k);
    scan3_kernel<<<n2k, 1024, 0, stream>>>(start, bsum, 2 * N);
    scatter_plain_kernel<<<e256, blk, 0, stream>>>(ei, pseudo, start, rank, erec, N, E);

    // ---- Layer 1 ----
    transform_mfma<0><<<tb, blk, 0, stream>>>(x, nullptr, Wt1, b1, y, agg1, N);
    msg_kernel<<<eb, blk, 0, stream>>>(erec, (const uint4*)y, (uint4*)msg, E);
    gather_kernel<<<gb, blk, 0, stream>>>(dstart, (const uint4*)msg, agg1, N, E);   // h1
    // ---- Layer 2: X = concat(h1, skip) ----
    transform_mfma<1><<<tb, blk, 0, stream>>>(agg1, skip, Wt1, b1, y, agg1, N);
    msg_kernel<<<eb, blk, 0, stream>>>(erec, (const uint4*)y, (uint4*)msg, E);
    gather_kernel<<<gb, blk, 0, stream>>>(dstart, (const uint4*)msg, agg1, N, E);   // h2
    // ---- Layer 3 -> d_out ----
    transform_mfma<2><<<tb, blk, 0, stream>>>(agg1, nullptr, Wt2, b2, y, out, N);
    msg_kernel<<<eb, blk, 0, stream>>>(erec, (const uint4*)y, (uint4*)msg, E);
    gather_kernel<<<gb, blk, 0, stream>>>(dstart, (const uint4*)msg, out, N, E);    // relu fused
}

// Round 10
// 265.323 us; speedup vs baseline: 1.6314x; 1.0482x over previous
//
#include <hip/hip_runtime.h>
#include <hip/hip_bf16.h>

// 3-layer SplineConv (3x3, degree 2, open spline). Atomic-free, fused T+M.
// Prep: dual counting sort (src & dst) via one 2N scan; edge rank captured in
//   the count pass (atomicAdd return) so scatter is atomic-free; packed float4
//   edge record {src, dpos, p0, p1} at the src-sorted slot.
// Per layer:
//   layer_tm (fused): block owns 64 nodes.
//     T phase: C[64][320] = X @ [W0..W8|root] (16x16x32 bf16 MFMA);
//       cols 0..287 -> sY LDS tile (bf16), cols 288..319 -> agg init (global).
//     M phase: the tile's contiguous src-CSR edge segment; 4 lanes/edge read
//       sY rows (ds_read_b128), msg = sum qa qb y; bf16x8 store to dst slot.
//   gather: 4 lanes/node, uint4 msg loads over contiguous dst segment; relu.
// y never touches global memory (saves ~29 MB write + L2 re-read per layer).

typedef __attribute__((ext_vector_type(8))) short short8;
typedef __attribute__((ext_vector_type(4))) float f32x4;

__device__ __forceinline__ float blo(unsigned u) {
    union { unsigned u; float f; } x; x.u = u << 16; return x.f;
}
__device__ __forceinline__ float bhi(unsigned u) {
    union { unsigned u; float f; } x; x.u = u & 0xffff0000u; return x.f;
}
__device__ __forceinline__ unsigned short f2bf(float f) {
    union { float f; unsigned u; } x; x.f = f;
    unsigned r = x.u + 0x7fffu + ((x.u >> 16) & 1u);   // RNE
    return (unsigned short)(r >> 16);
}
__device__ __forceinline__ short8 cvt8(const float* p) {
    float4 a = *(const float4*)p;
    float4 b = *(const float4*)(p + 4);
    short8 r;
    r[0] = (short)f2bf(a.x); r[1] = (short)f2bf(a.y);
    r[2] = (short)f2bf(a.z); r[3] = (short)f2bf(a.w);
    r[4] = (short)f2bf(b.x); r[5] = (short)f2bf(b.y);
    r[6] = (short)f2bf(b.z); r[7] = (short)f2bf(b.w);
    return r;
}

#define YROW 296   // sY row stride in shorts (592 B = 37 uint4, 16B-aligned)

// MODE 0: X = Xa [N,64];  MODE 1: X = [Xa[N,32]|Xb[N,32]];  MODE 2: X = Xa [N,32]
template<int MODE>
__global__ __launch_bounds__(256)
void layer_tm(const float* __restrict__ Xa, const float* __restrict__ Xb,
              const unsigned short* __restrict__ Wt,  // [320][CIN] bf16
              const float* __restrict__ bias,
              const int* __restrict__ sstart,         // src-CSR exclusive starts
              const float4* __restrict__ erec,
              float* __restrict__ agg, uint4* __restrict__ msg4, int N, int E)
{
    const int CIN = (MODE == 2) ? 32 : 64;
    __shared__ __align__(16) unsigned short sY[64 * YROW];   // 37,888 B

    const int t    = threadIdx.x;
    const int wv   = t >> 6;
    const int lane = t & 63;
    const int lc   = lane & 15;
    const int q    = lane >> 4;
    const int n0   = blockIdx.x * 64;
    const int base = n0 + wv * 16;

    // ---- T phase: A fragments from global X (fp32 -> bf16 in-reg) ----
    int na = base + lc;
    if (na >= N) na = N - 1;
    short8 a0, a1;
    if (MODE == 0) {
        const float* p = Xa + (size_t)na * 64 + q * 8;
        a0 = cvt8(p);
        a1 = cvt8(p + 32);
    } else if (MODE == 1) {
        a0 = cvt8(Xa + (size_t)na * 32 + q * 8);
        a1 = cvt8(Xb + (size_t)na * 32 + q * 8);
    } else {
        a0 = cvt8(Xa + (size_t)na * 32 + q * 8);
    }

    f32x4 acc[20];
    #pragma unroll
    for (int nt = 0; nt < 20; ++nt) acc[nt] = (f32x4){0.f, 0.f, 0.f, 0.f};

    #pragma unroll
    for (int nt = 0; nt < 20; ++nt) {
        const unsigned short* wp = Wt + ((size_t)(nt * 16 + lc)) * CIN + q * 8;
        acc[nt] = __builtin_amdgcn_mfma_f32_16x16x32_bf16(a0, *(const short8*)wp, acc[nt], 0, 0, 0);
        if (MODE != 2)
            acc[nt] = __builtin_amdgcn_mfma_f32_16x16x32_bf16(a1, *(const short8*)(wp + 32), acc[nt], 0, 0, 0);
    }

    // epilogue: y tile -> LDS (write even for clamped tail rows: no edges use them)
    #pragma unroll
    for (int nt = 0; nt < 18; ++nt) {
        #pragma unroll
        for (int r = 0; r < 4; ++r) {
            int nl = wv * 16 + q * 4 + r;
            sY[nl * YROW + nt * 16 + lc] = f2bf(acc[nt][r]);
        }
    }
    #pragma unroll
    for (int nt = 18; nt < 20; ++nt) {
        int c = (nt - 18) * 16 + lc;
        #pragma unroll
        for (int r = 0; r < 4; ++r) {
            int n = base + q * 4 + r;
            if (n < N) agg[(size_t)n * 32 + c] = acc[nt][r] + bias[c];
        }
    }
    __syncthreads();

    // ---- M phase: this tile's src-CSR edge segment ----
    const int e0 = sstart[n0];
    const int e1 = (n0 + 64 < N) ? sstart[n0 + 64] : E;
    const int l  = t & 3;

    for (int e = e0 + (t >> 2); e < e1; e += 64) {
        const float4 r = erec[e];
        const int srcl = __float_as_int(r.x) - n0;
        const int dp   = __float_as_int(r.y);
        const float p0 = r.z, p1 = r.w;

        const float qb[3] = {0.5f * (1.f - p0) * (1.f - p0), -p0 * p0 + p0 + 0.5f, 0.5f * p0 * p0};
        const float qa[3] = {0.5f * (1.f - p1) * (1.f - p1), -p1 * p1 + p1 + 0.5f, 0.5f * p1 * p1};

        const uint4* yb = (const uint4*)(sY + srcl * YROW) + l;
        float s[8] = {0.f, 0.f, 0.f, 0.f, 0.f, 0.f, 0.f, 0.f};
        #pragma unroll
        for (int a = 0; a < 3; ++a) {
            float z[8] = {0.f, 0.f, 0.f, 0.f, 0.f, 0.f, 0.f, 0.f};
            #pragma unroll
            for (int b = 0; b < 3; ++b) {
                uint4 v = yb[(a * 3 + b) * 4];
                const float cw = qb[b];
                z[0] = fmaf(cw, blo(v.x), z[0]); z[1] = fmaf(cw, bhi(v.x), z[1]);
                z[2] = fmaf(cw, blo(v.y), z[2]); z[3] = fmaf(cw, bhi(v.y), z[3]);
                z[4] = fmaf(cw, blo(v.z), z[4]); z[5] = fmaf(cw, bhi(v.z), z[5]);
                z[6] = fmaf(cw, blo(v.w), z[6]); z[7] = fmaf(cw, bhi(v.w), z[7]);
            }
            #pragma unroll
            for (int j = 0; j < 8; ++j) s[j] = fmaf(qa[a], z[j], s[j]);
        }

        union { uint4 u; __hip_bfloat162 h[4]; } o;
        #pragma unroll
        for (int j = 0; j < 4; ++j)
            o.h[j] = __float22bfloat162_rn(float2{s[2 * j], s[2 * j + 1]});
        msg4[(size_t)dp * 4 + l] = o.u;
    }
}

// gather: 4 lanes/node; segment = [dstart[n], dstart[n+1]) - E  (last end = E)
__global__ __launch_bounds__(256)
void gather_kernel(const int* __restrict__ dstart,  // exclusive starts, +E offset
                   const uint4* __restrict__ msg4,
                   float* __restrict__ agg, int N, int E)
{
    const int t = threadIdx.x;
    const int n = blockIdx.x * 64 + (t >> 2);
    if (n >= N) return;
    const int l = t & 3;

    const int e0 = dstart[n] - E;
    const int e1 = ((n + 1 < N) ? dstart[n + 1] : 2 * E) - E;

    float4* ap = (float4*)(agg + (size_t)n * 32 + l * 8);
    float4 A = ap[0], B = ap[1];
    const uint4* mp = msg4 + l;
    for (int e = e0; e < e1; ++e) {
        uint4 v = mp[(size_t)e * 4];
        A.x += blo(v.x); A.y += bhi(v.x); A.z += blo(v.y); A.w += bhi(v.y);
        B.x += blo(v.z); B.y += bhi(v.z); B.z += blo(v.w); B.w += bhi(v.w);
    }
    A.x = fmaxf(A.x, 0.f); A.y = fmaxf(A.y, 0.f); A.z = fmaxf(A.z, 0.f); A.w = fmaxf(A.w, 0.f);
    B.x = fmaxf(B.x, 0.f); B.y = fmaxf(B.y, 0.f); B.z = fmaxf(B.z, 0.f); B.w = fmaxf(B.w, 0.f);
    ap[0] = A; ap[1] = B;
}

// ---------- prep ----------

// merged: zero the 2N histogram AND build both bf16 weight panels
__global__ __launch_bounds__(256)
void init_kernel(int* __restrict__ hist, int n2,
                 const float* __restrict__ W1, const float* __restrict__ root1,
                 const float* __restrict__ W2, const float* __restrict__ root2,
                 unsigned short* __restrict__ Wt1, unsigned short* __restrict__ Wt2)
{
    int i = blockIdx.x * 256 + threadIdx.x;
    if (i < n2) { hist[i] = 0; return; }
    int j = i - n2;
    if (j < 320 * 64) {
        int col = j / 64, k = j % 64;
        float v = (col < 288) ? W1[((size_t)(col >> 5) * 64 + k) * 32 + (col & 31)]
                              : root1[(size_t)k * 32 + (col - 288)];
        Wt1[j] = f2bf(v);
    } else if (j < 320 * 96) {
        int jj = j - 320 * 64;
        int col = jj / 32, k = jj % 32;
        float v = (col < 288) ? W2[((size_t)(col >> 5) * 32 + k) * 32 + (col & 31)]
                              : root2[(size_t)k * 32 + (col - 288)];
        Wt2[jj] = f2bf(v);
    }
}

// count both bins AND capture each edge's rank (atomicAdd return is free)
__global__ __launch_bounds__(256)
void count_rank_kernel(const int* __restrict__ ei, int* __restrict__ hist,
                       uint2* __restrict__ rank, int N, int E)
{
    int e = blockIdx.x * 256 + threadIdx.x;
    if (e >= E) return;
    unsigned rs = atomicAdd(&hist[ei[e]], 1);
    unsigned rd = atomicAdd(&hist[N + ei[E + e]], 1);
    rank[e] = uint2{rs, rd};
}

__global__ __launch_bounds__(1024)
void scan1_kernel(int* __restrict__ hist, int* __restrict__ bsum, int n)
{
    __shared__ int s[1024];
    int tid = threadIdx.x;
    int i = blockIdx.x * 1024 + tid;
    int v = (i < n) ? hist[i] : 0;
    s[tid] = v;
    __syncthreads();
    for (int off = 1; off < 1024; off <<= 1) {
        int add = (tid >= off) ? s[tid - off] : 0;
        __syncthreads();
        s[tid] += add;
        __syncthreads();
    }
    if (i < n) hist[i] = s[tid] - v;           // exclusive within block
    if (tid == 1023) bsum[blockIdx.x] = s[1023];
}

// folds the tiny scan2: each block reduces bsum[0..blockIdx) in-LDS (nb<=128)
__global__ __launch_bounds__(1024)
void scan3_kernel(int* __restrict__ hist, const int* __restrict__ bsum, int n)
{
    __shared__ int sred[128];
    int tid = threadIdx.x;
    int b = blockIdx.x;
    if (tid < 128) sred[tid] = (tid < b) ? bsum[tid] : 0;
    __syncthreads();
    for (int off = 64; off > 0; off >>= 1) {
        if (tid < off) sred[tid] += sred[tid + off];
        __syncthreads();
    }
    int pre = sred[0];
    int i = b * 1024 + tid;
    if (i < n) hist[i] += pre;
}

// no atomics: positions from exclusive starts + pre-captured ranks
__global__ __launch_bounds__(256)
void scatter_plain_kernel(const int* __restrict__ ei, const float* __restrict__ pseudo,
                          const int* __restrict__ start, const uint2* __restrict__ rank,
                          float4* __restrict__ erec, int N, int E)
{
    int e = blockIdx.x * 256 + threadIdx.x;
    if (e >= E) return;
    int sv = ei[e];
    int dv = ei[E + e];
    uint2 rk = rank[e];
    int ps = start[sv] + (int)rk.x;
    int pd = start[N + dv] + (int)rk.y - E;
    float4 r;
    r.x = __int_as_float(sv);
    r.y = __int_as_float(pd);
    r.z = pseudo[2 * (size_t)e];
    r.w = pseudo[2 * (size_t)e + 1];
    erec[ps] = r;
}

extern "C" void kernel_launch(void* const* d_in, const int* in_sizes, int n_in,
                              void* d_out, int out_size, void* d_ws, size_t ws_size,
                              hipStream_t stream) {
    const float* x      = (const float*)d_in[0];
    const int*   ei     = (const int*)  d_in[1];
    const float* pseudo = (const float*)d_in[2];
    const float* skip   = (const float*)d_in[3];
    const float* W1     = (const float*)d_in[4];
    const float* root1  = (const float*)d_in[5];
    const float* b1     = (const float*)d_in[6];
    const float* W2     = (const float*)d_in[7];
    const float* root2  = (const float*)d_in[8];
    const float* b2     = (const float*)d_in[9];

    const int N = in_sizes[0] / 64;
    const int E = in_sizes[1] / 2;
    float* out = (float*)d_out;

    // ws (~42 MB): msg[E*32 bf16] agg1[N*32 f32] erec[E f4] rank[E uint2]
    //              start[2N] bsum[256] Wt1[320*64 bf16] Wt2[320*32 bf16]
    unsigned short* msg = (unsigned short*)d_ws;
    float*  agg1  = (float*)(msg + (size_t)E * 32);
    float4* erec  = (float4*)(agg1 + (size_t)N * 32);
    uint2*  rank  = (uint2*)(erec + E);
    int*    start = (int*)(rank + E);
    int*    bsum  = start + 2 * N;
    unsigned short* Wt1 = (unsigned short*)(bsum + 256);
    unsigned short* Wt2 = Wt1 + 320 * 64;

    const dim3 blk(256);
    const int tb   = (N + 63) / 64;
    const int gb   = (N + 63) / 64;
    const int e256 = (E + 255) / 256;
    const int n2k  = (2 * N + 1023) / 1024;        // <=128 blocks (scan3 prefix cap)
    const int itot = 2 * N + 320 * 96;
    int* dstart = start + N;   // dst-bin exclusive starts (+E offset)

    // ---- prep (5 launches) ----
    init_kernel<<<(itot + 255) / 256, blk, 0, stream>>>(start, 2 * N, W1, root1, W2, root2, Wt1, Wt2);
    count_rank_kernel<<<e256, blk, 0, stream>>>(ei, start, rank, N, E);
    scan1_kernel<<<n2k, 1024, 0, stream>>>(start, bsum, 2 * N);
    scan3_kernel<<<n2k, 1024, 0, stream>>>(start, bsum, 2 * N);
    scatter_plain_kernel<<<e256, blk, 0, stream>>>(ei, pseudo, start, rank, erec, N, E);

    // ---- Layer 1 ----
    layer_tm<0><<<tb, blk, 0, stream>>>(x, nullptr, Wt1, b1, start, erec, agg1, (uint4*)msg, N, E);
    gather_kernel<<<gb, blk, 0, stream>>>(dstart, (const uint4*)msg, agg1, N, E);   // h1
    // ---- Layer 2: X = concat(h1, skip); agg in-place (each block rewrites only its own rows) ----
    layer_tm<1><<<tb, blk, 0, stream>>>(agg1, skip, Wt1, b1, start, erec, agg1, (uint4*)msg, N, E);
    gather_kernel<<<gb, blk, 0, stream>>>(dstart, (const uint4*)msg, agg1, N, E);   // h2
    // ---- Layer 3 -> d_out ----
    layer_tm<2><<<tb, blk, 0, stream>>>(agg1, nullptr, Wt2, b2, start, erec, out, (uint4*)msg, N, E);
    gather_kernel<<<gb, blk, 0, stream>>>(dstart, (const uint4*)msg, out, N, E);    // relu fused
}

// Round 11
// 264.067 us; speedup vs baseline: 1.6391x; 1.0048x over previous
//
#include <hip/hip_runtime.h>
#include <hip/hip_bf16.h>

// 3-layer SplineConv (3x3, degree 2, open spline). Atomic-free, deep fusion.
// Prep: dual counting sort (src & dst), one 2N scan; edge rank captured in the
//   count pass so the scatter is atomic-free; packed float4 edge record
//   {src, dpos, p0, p1} at the src-sorted slot.
// Layers:
//   L1 layer_tm<0>: X=x. MFMA C[64][320]=X@[W0..W8|root]; y tile -> LDS;
//     M phase: src-CSR segment, 4 lanes/edge read sY, msg bf16x8 -> dst slot.
//   L2/L3 layer_gtm: gather FUSED into the T phase: lane (q,lc) builds its own
//     A-frag channels by summing msgIn[e*4+q] over node (base+lc)'s dst
//     segment + root term, relu, pack bf16. h never touches global.
//   final gather: out = relu(agg3 + sum msg rows).
// msg ping-pongs msgA/msgB (cross-block read/write race otherwise).

typedef __attribute__((ext_vector_type(8))) short short8;
typedef __attribute__((ext_vector_type(4))) float f32x4;

__device__ __forceinline__ float blo(unsigned u) {
    union { unsigned u; float f; } x; x.u = u << 16; return x.f;
}
__device__ __forceinline__ float bhi(unsigned u) {
    union { unsigned u; float f; } x; x.u = u & 0xffff0000u; return x.f;
}
__device__ __forceinline__ unsigned short f2bf(float f) {
    union { float f; unsigned u; } x; x.f = f;
    unsigned r = x.u + 0x7fffu + ((x.u >> 16) & 1u);   // RNE
    return (unsigned short)(r >> 16);
}
__device__ __forceinline__ short8 cvt8(const float* p) {
    float4 a = *(const float4*)p;
    float4 b = *(const float4*)(p + 4);
    short8 r;
    r[0] = (short)f2bf(a.x); r[1] = (short)f2bf(a.y);
    r[2] = (short)f2bf(a.z); r[3] = (short)f2bf(a.w);
    r[4] = (short)f2bf(b.x); r[5] = (short)f2bf(b.y);
    r[6] = (short)f2bf(b.z); r[7] = (short)f2bf(b.w);
    return r;
}

#define YROW 296   // sY row stride in shorts (592 B, 16B-aligned)

// ---- shared M phase: compute msgs for the block's src-CSR segment from sY ----
__device__ __forceinline__ void m_phase(const unsigned short* sY,
                                        const int* __restrict__ sstart,
                                        const float4* __restrict__ erec,
                                        uint4* __restrict__ msgOut,
                                        int n0, int t, int N, int E)
{
    const int e0 = sstart[n0];
    const int e1 = (n0 + 64 < N) ? sstart[n0 + 64] : E;
    const int l  = t & 3;

    for (int e = e0 + (t >> 2); e < e1; e += 64) {
        const float4 r = erec[e];
        const int srcl = __float_as_int(r.x) - n0;
        const int dp   = __float_as_int(r.y);
        const float p0 = r.z, p1 = r.w;

        const float qb[3] = {0.5f * (1.f - p0) * (1.f - p0), -p0 * p0 + p0 + 0.5f, 0.5f * p0 * p0};
        const float qa[3] = {0.5f * (1.f - p1) * (1.f - p1), -p1 * p1 + p1 + 0.5f, 0.5f * p1 * p1};

        const uint4* yb = (const uint4*)(sY + srcl * YROW) + l;
        float s[8] = {0.f, 0.f, 0.f, 0.f, 0.f, 0.f, 0.f, 0.f};
        #pragma unroll
        for (int a = 0; a < 3; ++a) {
            float z[8] = {0.f, 0.f, 0.f, 0.f, 0.f, 0.f, 0.f, 0.f};
            #pragma unroll
            for (int b = 0; b < 3; ++b) {
                uint4 v = yb[(a * 3 + b) * 4];
                const float cw = qb[b];
                z[0] = fmaf(cw, blo(v.x), z[0]); z[1] = fmaf(cw, bhi(v.x), z[1]);
                z[2] = fmaf(cw, blo(v.y), z[2]); z[3] = fmaf(cw, bhi(v.y), z[3]);
                z[4] = fmaf(cw, blo(v.z), z[4]); z[5] = fmaf(cw, bhi(v.z), z[5]);
                z[6] = fmaf(cw, blo(v.w), z[6]); z[7] = fmaf(cw, bhi(v.w), z[7]);
            }
            #pragma unroll
            for (int j = 0; j < 8; ++j) s[j] = fmaf(qa[a], z[j], s[j]);
        }

        union { uint4 u; __hip_bfloat162 h[4]; } o;
        #pragma unroll
        for (int j = 0; j < 4; ++j)
            o.h[j] = __float22bfloat162_rn(float2{s[2 * j], s[2 * j + 1]});
        msgOut[(size_t)dp * 4 + l] = o.u;
    }
}

// ---- shared T core: MFMA + epilogue (sY + aggOut root term) ----
template<int NHALF>  // 2: K=64 (a0,a1), 1: K=32 (a0)
__device__ __forceinline__ void t_core(short8 a0, short8 a1,
                                       const unsigned short* __restrict__ Wt,
                                       const float* __restrict__ bias,
                                       unsigned short* sY, float* __restrict__ aggOut,
                                       int base, int wv, int lc, int q, int N)
{
    const int CIN = NHALF * 32;
    f32x4 acc[20];
    #pragma unroll
    for (int nt = 0; nt < 20; ++nt) acc[nt] = (f32x4){0.f, 0.f, 0.f, 0.f};

    #pragma unroll
    for (int nt = 0; nt < 20; ++nt) {
        const unsigned short* wp = Wt + ((size_t)(nt * 16 + lc)) * CIN + q * 8;
        acc[nt] = __builtin_amdgcn_mfma_f32_16x16x32_bf16(a0, *(const short8*)wp, acc[nt], 0, 0, 0);
        if (NHALF == 2)
            acc[nt] = __builtin_amdgcn_mfma_f32_16x16x32_bf16(a1, *(const short8*)(wp + 32), acc[nt], 0, 0, 0);
    }

    #pragma unroll
    for (int nt = 0; nt < 18; ++nt) {
        #pragma unroll
        for (int r = 0; r < 4; ++r) {
            int nl = wv * 16 + q * 4 + r;
            sY[nl * YROW + nt * 16 + lc] = f2bf(acc[nt][r]);
        }
    }
    #pragma unroll
    for (int nt = 18; nt < 20; ++nt) {
        int c = (nt - 18) * 16 + lc;
        #pragma unroll
        for (int r = 0; r < 4; ++r) {
            int n = base + q * 4 + r;
            if (n < N) aggOut[(size_t)n * 32 + c] = acc[nt][r] + bias[c];
        }
    }
}

// L1: X = x [N,64] from global
__global__ __launch_bounds__(256)
void layer_tm0(const float* __restrict__ Xa,
               const unsigned short* __restrict__ Wt, const float* __restrict__ bias,
               const int* __restrict__ sstart, const float4* __restrict__ erec,
               float* __restrict__ aggOut, uint4* __restrict__ msgOut, int N, int E)
{
    __shared__ __align__(16) unsigned short sY[64 * YROW];
    const int t = threadIdx.x, wv = t >> 6, lane = t & 63;
    const int lc = lane & 15, q = lane >> 4;
    const int n0 = blockIdx.x * 64, base = n0 + wv * 16;

    int na = base + lc;
    if (na >= N) na = N - 1;
    const float* p = Xa + (size_t)na * 64 + q * 8;
    short8 a0 = cvt8(p);
    short8 a1 = cvt8(p + 32);

    t_core<2>(a0, a1, Wt, bias, sY, aggOut, base, wv, lc, q, N);
    __syncthreads();
    m_phase(sY, sstart, erec, msgOut, n0, t, N, E);
}

// L2 (MODE 1): X = [relu(aggPrev + gather msgIn) | skip]; L3 (MODE 2): X = relu(...)
template<int MODE>
__global__ __launch_bounds__(256)
void layer_gtm(const float* __restrict__ aggPrev, const float* __restrict__ skipv,
               const unsigned short* __restrict__ Wt, const float* __restrict__ bias,
               const int* __restrict__ sstart, const int* __restrict__ dstart,
               const float4* __restrict__ erec,
               const uint4* __restrict__ msgIn, uint4* __restrict__ msgOut,
               float* __restrict__ aggOut, int N, int E)
{
    __shared__ __align__(16) unsigned short sY[64 * YROW];
    const int t = threadIdx.x, wv = t >> 6, lane = t & 63;
    const int lc = lane & 15, q = lane >> 4;
    const int n0 = blockIdx.x * 64, base = n0 + wv * 16;

    int na = base + lc;
    if (na >= N) na = N - 1;

    // fused gather: this lane's 8 channels (q*8..q*8+7) of node na
    const float* ap = aggPrev + (size_t)na * 32 + q * 8;
    float4 r0 = *(const float4*)ap;
    float4 r1 = *(const float4*)(ap + 4);
    float h[8] = {r0.x, r0.y, r0.z, r0.w, r1.x, r1.y, r1.z, r1.w};
    const int ge0 = dstart[na] - E;
    const int ge1 = ((na + 1 < N) ? dstart[na + 1] : 2 * E) - E;
    for (int e = ge0; e < ge1; ++e) {
        uint4 v = msgIn[(size_t)e * 4 + q];
        h[0] += blo(v.x); h[1] += bhi(v.x); h[2] += blo(v.y); h[3] += bhi(v.y);
        h[4] += blo(v.z); h[5] += bhi(v.z); h[6] += blo(v.w); h[7] += bhi(v.w);
    }
    union { short8 v; __hip_bfloat162 h2[4]; } pk;
    #pragma unroll
    for (int j = 0; j < 4; ++j)
        pk.h2[j] = __float22bfloat162_rn(float2{fmaxf(h[2 * j], 0.f), fmaxf(h[2 * j + 1], 0.f)});
    short8 a0 = pk.v;
    short8 a1;
    if (MODE == 1) a1 = cvt8(skipv + (size_t)na * 32 + q * 8);

    t_core<(MODE == 1) ? 2 : 1>(a0, a1, Wt, bias, sY, aggOut, base, wv, lc, q, N);
    __syncthreads();
    m_phase(sY, sstart, erec, msgOut, n0, t, N, E);
}

// final gather: out = relu(out + sum msg rows)  (in-place on root term)
__global__ __launch_bounds__(256)
void gather_kernel(const int* __restrict__ dstart, const uint4* __restrict__ msg4,
                   float* __restrict__ agg, int N, int E)
{
    const int t = threadIdx.x;
    const int n = blockIdx.x * 64 + (t >> 2);
    if (n >= N) return;
    const int l = t & 3;

    const int e0 = dstart[n] - E;
    const int e1 = ((n + 1 < N) ? dstart[n + 1] : 2 * E) - E;

    float4* ap = (float4*)(agg + (size_t)n * 32 + l * 8);
    float4 A = ap[0], B = ap[1];
    const uint4* mp = msg4 + l;
    for (int e = e0; e < e1; ++e) {
        uint4 v = mp[(size_t)e * 4];
        A.x += blo(v.x); A.y += bhi(v.x); A.z += blo(v.y); A.w += bhi(v.y);
        B.x += blo(v.z); B.y += bhi(v.z); B.z += blo(v.w); B.w += bhi(v.w);
    }
    A.x = fmaxf(A.x, 0.f); A.y = fmaxf(A.y, 0.f); A.z = fmaxf(A.z, 0.f); A.w = fmaxf(A.w, 0.f);
    B.x = fmaxf(B.x, 0.f); B.y = fmaxf(B.y, 0.f); B.z = fmaxf(B.z, 0.f); B.w = fmaxf(B.w, 0.f);
    ap[0] = A; ap[1] = B;
}

// ---------- prep ----------

__global__ __launch_bounds__(256)
void init_kernel(int* __restrict__ hist, int n2,
                 const float* __restrict__ W1, const float* __restrict__ root1,
                 const float* __restrict__ W2, const float* __restrict__ root2,
                 unsigned short* __restrict__ Wt1, unsigned short* __restrict__ Wt2)
{
    int i = blockIdx.x * 256 + threadIdx.x;
    if (i < n2) { hist[i] = 0; return; }
    int j = i - n2;
    if (j < 320 * 64) {
        int col = j / 64, k = j % 64;
        float v = (col < 288) ? W1[((size_t)(col >> 5) * 64 + k) * 32 + (col & 31)]
                              : root1[(size_t)k * 32 + (col - 288)];
        Wt1[j] = f2bf(v);
    } else if (j < 320 * 96) {
        int jj = j - 320 * 64;
        int col = jj / 32, k = jj % 32;
        float v = (col < 288) ? W2[((size_t)(col >> 5) * 32 + k) * 32 + (col & 31)]
                              : root2[(size_t)k * 32 + (col - 288)];
        Wt2[jj] = f2bf(v);
    }
}

__global__ __launch_bounds__(256)
void count_rank_kernel(const int* __restrict__ ei, int* __restrict__ hist,
                       uint2* __restrict__ rank, int N, int E)
{
    int e = blockIdx.x * 256 + threadIdx.x;
    if (e >= E) return;
    unsigned rs = atomicAdd(&hist[ei[e]], 1);
    unsigned rd = atomicAdd(&hist[N + ei[E + e]], 1);
    rank[e] = uint2{rs, rd};
}

__global__ __launch_bounds__(1024)
void scan1_kernel(int* __restrict__ hist, int* __restrict__ bsum, int n)
{
    __shared__ int s[1024];
    int tid = threadIdx.x;
    int i = blockIdx.x * 1024 + tid;
    int v = (i < n) ? hist[i] : 0;
    s[tid] = v;
    __syncthreads();
    for (int off = 1; off < 1024; off <<= 1) {
        int add = (tid >= off) ? s[tid - off] : 0;
        __syncthreads();
        s[tid] += add;
        __syncthreads();
    }
    if (i < n) hist[i] = s[tid] - v;
    if (tid == 1023) bsum[blockIdx.x] = s[1023];
}

__global__ __launch_bounds__(1024)
void scan3_kernel(int* __restrict__ hist, const int* __restrict__ bsum, int n)
{
    __shared__ int sred[128];
    int tid = threadIdx.x;
    int b = blockIdx.x;
    if (tid < 128) sred[tid] = (tid < b) ? bsum[tid] : 0;
    __syncthreads();
    for (int off = 64; off > 0; off >>= 1) {
        if (tid < off) sred[tid] += sred[tid + off];
        __syncthreads();
    }
    int pre = sred[0];
    int i = b * 1024 + tid;
    if (i < n) hist[i] += pre;
}

__global__ __launch_bounds__(256)
void scatter_plain_kernel(const int* __restrict__ ei, const float* __restrict__ pseudo,
                          const int* __restrict__ start, const uint2* __restrict__ rank,
                          float4* __restrict__ erec, int N, int E)
{
    int e = blockIdx.x * 256 + threadIdx.x;
    if (e >= E) return;
    int sv = ei[e];
    int dv = ei[E + e];
    uint2 rk = rank[e];
    int ps = start[sv] + (int)rk.x;
    int pd = start[N + dv] + (int)rk.y - E;
    float4 r;
    r.x = __int_as_float(sv);
    r.y = __int_as_float(pd);
    r.z = pseudo[2 * (size_t)e];
    r.w = pseudo[2 * (size_t)e + 1];
    erec[ps] = r;
}

extern "C" void kernel_launch(void* const* d_in, const int* in_sizes, int n_in,
                              void* d_out, int out_size, void* d_ws, size_t ws_size,
                              hipStream_t stream) {
    const float* x      = (const float*)d_in[0];
    const int*   ei     = (const int*)  d_in[1];
    const float* pseudo = (const float*)d_in[2];
    const float* skip   = (const float*)d_in[3];
    const float* W1     = (const float*)d_in[4];
    const float* root1  = (const float*)d_in[5];
    const float* b1     = (const float*)d_in[6];
    const float* W2     = (const float*)d_in[7];
    const float* root2  = (const float*)d_in[8];
    const float* b2     = (const float*)d_in[9];

    const int N = in_sizes[0] / 64;
    const int E = in_sizes[1] / 2;
    float* out = (float*)d_out;

    // ws (~71 MB): msgA[E*32 bf16] msgB[E*32 bf16] agg1[N*32] agg2[N*32]
    //              erec[E f4] start[2N] bsum[256] Wt1 Wt2; rank aliases msgB
    unsigned short* msgA = (unsigned short*)d_ws;
    unsigned short* msgB = msgA + (size_t)E * 32;
    float*  agg1  = (float*)(msgB + (size_t)E * 32);
    float*  agg2  = agg1 + (size_t)N * 32;
    float4* erec  = (float4*)(agg2 + (size_t)N * 32);
    int*    start = (int*)(erec + E);
    int*    bsum  = start + 2 * N;
    unsigned short* Wt1 = (unsigned short*)(bsum + 256);
    unsigned short* Wt2 = Wt1 + 320 * 64;
    uint2*  rank  = (uint2*)msgB;    // prep-only, dead before msgB first written

    const dim3 blk(256);
    const int tb   = (N + 63) / 64;
    const int gb   = (N + 63) / 64;
    const int e256 = (E + 255) / 256;
    const int n2k  = (2 * N + 1023) / 1024;   // <=128 (scan3 prefix cap)
    const int itot = 2 * N + 320 * 96;
    int* dstart = start + N;

    // ---- prep (5 launches) ----
    init_kernel<<<(itot + 255) / 256, blk, 0, stream>>>(start, 2 * N, W1, root1, W2, root2, Wt1, Wt2);
    count_rank_kernel<<<e256, blk, 0, stream>>>(ei, start, rank, N, E);
    scan1_kernel<<<n2k, 1024, 0, stream>>>(start, bsum, 2 * N);
    scan3_kernel<<<n2k, 1024, 0, stream>>>(start, bsum, 2 * N);
    scatter_plain_kernel<<<e256, blk, 0, stream>>>(ei, pseudo, start, rank, erec, N, E);

    // ---- layers (4 launches) ----
    layer_tm0<<<tb, blk, 0, stream>>>(x, Wt1, b1, start, erec, agg1, (uint4*)msgA, N, E);
    layer_gtm<1><<<tb, blk, 0, stream>>>(agg1, skip, Wt1, b1, start, dstart, erec,
                                         (const uint4*)msgA, (uint4*)msgB, agg2, N, E);
    layer_gtm<2><<<tb, blk, 0, stream>>>(agg2, nullptr, Wt2, b2, start, dstart, erec,
                                         (const uint4*)msgB, (uint4*)msgA, out, N, E);
    gather_kernel<<<gb, blk, 0, stream>>>(dstart, (const uint4*)msgA, out, N, E);
}

// Round 13
// 251.606 us; speedup vs baseline: 1.7203x; 1.0495x over previous
//
#include <hip/hip_runtime.h>
#include <hip/hip_bf16.h>

// 3-layer SplineConv (3x3, degree 2, open spline). Atomic-free, deep fusion.
// Round 12 retry (prior bench was an infra failure, not a kernel result).
// TN=32 node tiles (was 64): LDS 18.9 KB -> 8 blocks/CU by LDS, grid 1563,
//   acc regs halved -> latency hiding via occupancy.
//   Wave w owns row-half (w&1) and col-tile-group (w>>1): 10 of 20 col tiles.
// Prep: dual counting sort (src & dst), one 2N scan; rank captured in count
//   pass -> atomic-free scatter; packed float4 erec {src,dpos,p0,p1}.
// Layers: L1 tm0 (X=x global), L2/L3 gtm (gather fused: lane sums its own
//   8 channels of msgIn over its node's dst segment + root term, relu, bf16).
//   M phase: src-CSR segment, 4 lanes/edge read sY (LDS), msg -> dst slot.
// Final gather: out = relu(agg3 + sum msg rows).

typedef __attribute__((ext_vector_type(8))) short short8;
typedef __attribute__((ext_vector_type(4))) float f32x4;

__device__ __forceinline__ float blo(unsigned u) {
    union { unsigned u; float f; } x; x.u = u << 16; return x.f;
}
__device__ __forceinline__ float bhi(unsigned u) {
    union { unsigned u; float f; } x; x.u = u & 0xffff0000u; return x.f;
}
__device__ __forceinline__ unsigned short f2bf(float f) {
    union { float f; unsigned u; } x; x.f = f;
    unsigned r = x.u + 0x7fffu + ((x.u >> 16) & 1u);   // RNE
    return (unsigned short)(r >> 16);
}
__device__ __forceinline__ short8 cvt8(const float* p) {
    float4 a = *(const float4*)p;
    float4 b = *(const float4*)(p + 4);
    short8 r;
    r[0] = (short)f2bf(a.x); r[1] = (short)f2bf(a.y);
    r[2] = (short)f2bf(a.z); r[3] = (short)f2bf(a.w);
    r[4] = (short)f2bf(b.x); r[5] = (short)f2bf(b.y);
    r[6] = (short)f2bf(b.z); r[7] = (short)f2bf(b.w);
    return r;
}

#define YROW 296   // sY row stride in shorts (592 B, 16B-aligned)

// ---- M phase: msgs for the block's src-CSR segment, y from LDS ----
__device__ __forceinline__ void m_phase(const unsigned short* sY,
                                        const int* __restrict__ sstart,
                                        const float4* __restrict__ erec,
                                        uint4* __restrict__ msgOut,
                                        int n0, int t, int N, int E)
{
    const int e0 = sstart[n0];
    const int e1 = (n0 + 32 < N) ? sstart[n0 + 32] : E;
    const int l  = t & 3;

    for (int e = e0 + (t >> 2); e < e1; e += 64) {
        const float4 r = erec[e];
        const int srcl = __float_as_int(r.x) - n0;
        const int dp   = __float_as_int(r.y);
        const float p0 = r.z, p1 = r.w;

        const float qb[3] = {0.5f * (1.f - p0) * (1.f - p0), -p0 * p0 + p0 + 0.5f, 0.5f * p0 * p0};
        const float qa[3] = {0.5f * (1.f - p1) * (1.f - p1), -p1 * p1 + p1 + 0.5f, 0.5f * p1 * p1};

        const uint4* yb = (const uint4*)(sY + srcl * YROW) + l;
        float s[8] = {0.f, 0.f, 0.f, 0.f, 0.f, 0.f, 0.f, 0.f};
        #pragma unroll
        for (int a = 0; a < 3; ++a) {
            float z[8] = {0.f, 0.f, 0.f, 0.f, 0.f, 0.f, 0.f, 0.f};
            #pragma unroll
            for (int b = 0; b < 3; ++b) {
                uint4 v = yb[(a * 3 + b) * 4];
                const float cw = qb[b];
                z[0] = fmaf(cw, blo(v.x), z[0]); z[1] = fmaf(cw, bhi(v.x), z[1]);
                z[2] = fmaf(cw, blo(v.y), z[2]); z[3] = fmaf(cw, bhi(v.y), z[3]);
                z[4] = fmaf(cw, blo(v.z), z[4]); z[5] = fmaf(cw, bhi(v.z), z[5]);
                z[6] = fmaf(cw, blo(v.w), z[6]); z[7] = fmaf(cw, bhi(v.w), z[7]);
            }
            #pragma unroll
            for (int j = 0; j < 8; ++j) s[j] = fmaf(qa[a], z[j], s[j]);
        }

        union { uint4 u; __hip_bfloat162 h[4]; } o;
        #pragma unroll
        for (int j = 0; j < 4; ++j)
            o.h[j] = __float22bfloat162_rn(float2{s[2 * j], s[2 * j + 1]});
        msgOut[(size_t)dp * 4 + l] = o.u;
    }
}

// ---- T core (TN=32): wave owns row-half rh, col-tile-group cg (10 tiles) ----
template<int NHALF>  // 2: K=64, 1: K=32
__device__ __forceinline__ void t_core(short8 a0, short8 a1,
                                       const unsigned short* __restrict__ Wt,
                                       const float* __restrict__ bias,
                                       unsigned short* sY, float* __restrict__ aggOut,
                                       int n0, int rh, int cg, int lc, int q, int N)
{
    const int CIN = NHALF * 32;
    f32x4 acc[10];
    #pragma unroll
    for (int j = 0; j < 10; ++j) acc[j] = (f32x4){0.f, 0.f, 0.f, 0.f};

    #pragma unroll
    for (int j = 0; j < 10; ++j) {
        const int ti = cg * 10 + j;
        const unsigned short* wp = Wt + ((size_t)(ti * 16 + lc)) * CIN + q * 8;
        acc[j] = __builtin_amdgcn_mfma_f32_16x16x32_bf16(a0, *(const short8*)wp, acc[j], 0, 0, 0);
        if (NHALF == 2)
            acc[j] = __builtin_amdgcn_mfma_f32_16x16x32_bf16(a1, *(const short8*)(wp + 32), acc[j], 0, 0, 0);
    }

    #pragma unroll
    for (int j = 0; j < 10; ++j) {
        const int ti = cg * 10 + j;
        if (ti < 18) {
            #pragma unroll
            for (int r = 0; r < 4; ++r) {
                int nl = rh * 16 + q * 4 + r;
                sY[nl * YROW + ti * 16 + lc] = f2bf(acc[j][r]);
            }
        } else {
            int c = (ti - 18) * 16 + lc;
            float bv = bias[c];
            #pragma unroll
            for (int r = 0; r < 4; ++r) {
                int n = n0 + rh * 16 + q * 4 + r;
                if (n < N) aggOut[(size_t)n * 32 + c] = acc[j][r] + bv;
            }
        }
    }
}

// L1: X = x [N,64] from global
__global__ __launch_bounds__(256)
void layer_tm0(const float* __restrict__ Xa,
               const unsigned short* __restrict__ Wt, const float* __restrict__ bias,
               const int* __restrict__ sstart, const float4* __restrict__ erec,
               float* __restrict__ aggOut, uint4* __restrict__ msgOut, int N, int E)
{
    __shared__ __align__(16) unsigned short sY[32 * YROW];   // 18,944 B
    const int t = threadIdx.x, wv = t >> 6, lane = t & 63;
    const int lc = lane & 15, q = lane >> 4;
    const int rh = wv & 1, cg = wv >> 1;
    const int n0 = blockIdx.x * 32;

    int na = n0 + rh * 16 + lc;
    if (na >= N) na = N - 1;
    const float* p = Xa + (size_t)na * 64 + q * 8;
    short8 a0 = cvt8(p);
    short8 a1 = cvt8(p + 32);

    t_core<2>(a0, a1, Wt, bias, sY, aggOut, n0, rh, cg, lc, q, N);
    __syncthreads();
    m_phase(sY, sstart, erec, msgOut, n0, t, N, E);
}

// L2 (MODE 1): X = [relu(aggPrev + gather msgIn) | skip]; L3 (MODE 2): X = relu(...)
template<int MODE>
__global__ __launch_bounds__(256)
void layer_gtm(const float* __restrict__ aggPrev, const float* __restrict__ skipv,
               const unsigned short* __restrict__ Wt, const float* __restrict__ bias,
               const int* __restrict__ sstart, const int* __restrict__ dstart,
               const float4* __restrict__ erec,
               const uint4* __restrict__ msgIn, uint4* __restrict__ msgOut,
               float* __restrict__ aggOut, int N, int E)
{
    __shared__ __align__(16) unsigned short sY[32 * YROW];
    const int t = threadIdx.x, wv = t >> 6, lane = t & 63;
    const int lc = lane & 15, q = lane >> 4;
    const int rh = wv & 1, cg = wv >> 1;
    const int n0 = blockIdx.x * 32;

    int na = n0 + rh * 16 + lc;
    if (na >= N) na = N - 1;

    // fused gather: this lane's 8 channels (q*8..q*8+7) of node na
    const float* ap = aggPrev + (size_t)na * 32 + q * 8;
    float4 r0 = *(const float4*)ap;
    float4 r1 = *(const float4*)(ap + 4);
    float h[8] = {r0.x, r0.y, r0.z, r0.w, r1.x, r1.y, r1.z, r1.w};
    const int ge0 = dstart[na] - E;
    const int ge1 = ((na + 1 < N) ? dstart[na + 1] : 2 * E) - E;
    for (int e = ge0; e < ge1; ++e) {
        uint4 v = msgIn[(size_t)e * 4 + q];
        h[0] += blo(v.x); h[1] += bhi(v.x); h[2] += blo(v.y); h[3] += bhi(v.y);
        h[4] += blo(v.z); h[5] += bhi(v.z); h[6] += blo(v.w); h[7] += bhi(v.w);
    }
    union { short8 v; __hip_bfloat162 h2[4]; } pk;
    #pragma unroll
    for (int j = 0; j < 4; ++j)
        pk.h2[j] = __float22bfloat162_rn(float2{fmaxf(h[2 * j], 0.f), fmaxf(h[2 * j + 1], 0.f)});
    short8 a0 = pk.v;
    short8 a1;
    if (MODE == 1) a1 = cvt8(skipv + (size_t)na * 32 + q * 8);

    t_core<(MODE == 1) ? 2 : 1>(a0, a1, Wt, bias, sY, aggOut, n0, rh, cg, lc, q, N);
    __syncthreads();
    m_phase(sY, sstart, erec, msgOut, n0, t, N, E);
}

// final gather: out = relu(out + sum msg rows)  (in-place on root term)
__global__ __launch_bounds__(256)
void gather_kernel(const int* __restrict__ dstart, const uint4* __restrict__ msg4,
                   float* __restrict__ agg, int N, int E)
{
    const int t = threadIdx.x;
    const int n = blockIdx.x * 64 + (t >> 2);
    if (n >= N) return;
    const int l = t & 3;

    const int e0 = dstart[n] - E;
    const int e1 = ((n + 1 < N) ? dstart[n + 1] : 2 * E) - E;

    float4* ap = (float4*)(agg + (size_t)n * 32 + l * 8);
    float4 A = ap[0], B = ap[1];
    const uint4* mp = msg4 + l;
    for (int e = e0; e < e1; ++e) {
        uint4 v = mp[(size_t)e * 4];
        A.x += blo(v.x); A.y += bhi(v.x); A.z += blo(v.y); A.w += bhi(v.y);
        B.x += blo(v.z); B.y += bhi(v.z); B.z += blo(v.w); B.w += bhi(v.w);
    }
    A.x = fmaxf(A.x, 0.f); A.y = fmaxf(A.y, 0.f); A.z = fmaxf(A.z, 0.f); A.w = fmaxf(A.w, 0.f);
    B.x = fmaxf(B.x, 0.f); B.y = fmaxf(B.y, 0.f); B.z = fmaxf(B.z, 0.f); B.w = fmaxf(B.w, 0.f);
    ap[0] = A; ap[1] = B;
}

// ---------- prep ----------

__global__ __launch_bounds__(256)
void init_kernel(int* __restrict__ hist, int n2,
                 const float* __restrict__ W1, const float* __restrict__ root1,
                 const float* __restrict__ W2, const float* __restrict__ root2,
                 unsigned short* __restrict__ Wt1, unsigned short* __restrict__ Wt2)
{
    int i = blockIdx.x * 256 + threadIdx.x;
    if (i < n2) { hist[i] = 0; return; }
    int j = i - n2;
    if (j < 320 * 64) {
        int col = j / 64, k = j % 64;
        float v = (col < 288) ? W1[((size_t)(col >> 5) * 64 + k) * 32 + (col & 31)]
                              : root1[(size_t)k * 32 + (col - 288)];
        Wt1[j] = f2bf(v);
    } else if (j < 320 * 96) {
        int jj = j - 320 * 64;
        int col = jj / 32, k = jj % 32;
        float v = (col < 288) ? W2[((size_t)(col >> 5) * 32 + k) * 32 + (col & 31)]
                              : root2[(size_t)k * 32 + (col - 288)];
        Wt2[jj] = f2bf(v);
    }
}

__global__ __launch_bounds__(256)
void count_rank_kernel(const int* __restrict__ ei, int* __restrict__ hist,
                       uint2* __restrict__ rank, int N, int E)
{
    int e = blockIdx.x * 256 + threadIdx.x;
    if (e >= E) return;
    unsigned rs = atomicAdd(&hist[ei[e]], 1);
    unsigned rd = atomicAdd(&hist[N + ei[E + e]], 1);
    rank[e] = uint2{rs, rd};
}

__global__ __launch_bounds__(1024)
void scan1_kernel(int* __restrict__ hist, int* __restrict__ bsum, int n)
{
    __shared__ int s[1024];
    int tid = threadIdx.x;
    int i = blockIdx.x * 1024 + tid;
    int v = (i < n) ? hist[i] : 0;
    s[tid] = v;
    __syncthreads();
    for (int off = 1; off < 1024; off <<= 1) {
        int add = (tid >= off) ? s[tid - off] : 0;
        __syncthreads();
        s[tid] += add;
        __syncthreads();
    }
    if (i < n) hist[i] = s[tid] - v;
    if (tid == 1023) bsum[blockIdx.x] = s[1023];
}

__global__ __launch_bounds__(1024)
void scan3_kernel(int* __restrict__ hist, const int* __restrict__ bsum, int n)
{
    __shared__ int sred[128];
    int tid = threadIdx.x;
    int b = blockIdx.x;
    if (tid < 128) sred[tid] = (tid < b) ? bsum[tid] : 0;
    __syncthreads();
    for (int off = 64; off > 0; off >>= 1) {
        if (tid < off) sred[tid] += sred[tid + off];
        __syncthreads();
    }
    int pre = sred[0];
    int i = b * 1024 + tid;
    if (i < n) hist[i] += pre;
}

__global__ __launch_bounds__(256)
void scatter_plain_kernel(const int* __restrict__ ei, const float* __restrict__ pseudo,
                          const int* __restrict__ start, const uint2* __restrict__ rank,
                          float4* __restrict__ erec, int N, int E)
{
    int e = blockIdx.x * 256 + threadIdx.x;
    if (e >= E) return;
    int sv = ei[e];
    int dv = ei[E + e];
    uint2 rk = rank[e];
    int ps = start[sv] + (int)rk.x;
    int pd = start[N + dv] + (int)rk.y - E;
    float4 r;
    r.x = __int_as_float(sv);
    r.y = __int_as_float(pd);
    r.z = pseudo[2 * (size_t)e];
    r.w = pseudo[2 * (size_t)e + 1];
    erec[ps] = r;
}

extern "C" void kernel_launch(void* const* d_in, const int* in_sizes, int n_in,
                              void* d_out, int out_size, void* d_ws, size_t ws_size,
                              hipStream_t stream) {
    const float* x      = (const float*)d_in[0];
    const int*   ei     = (const int*)  d_in[1];
    const float* pseudo = (const float*)d_in[2];
    const float* skip   = (const float*)d_in[3];
    const float* W1     = (const float*)d_in[4];
    const float* root1  = (const float*)d_in[5];
    const float* b1     = (const float*)d_in[6];
    const float* W2     = (const float*)d_in[7];
    const float* root2  = (const float*)d_in[8];
    const float* b2     = (const float*)d_in[9];

    const int N = in_sizes[0] / 64;
    const int E = in_sizes[1] / 2;
    float* out = (float*)d_out;

    // ws (~71 MB): msgA[E*32 bf16] msgB[E*32 bf16] agg1[N*32] agg2[N*32]
    //              erec[E f4] start[2N] bsum[256] Wt1 Wt2; rank aliases msgB
    unsigned short* msgA = (unsigned short*)d_ws;
    unsigned short* msgB = msgA + (size_t)E * 32;
    float*  agg1  = (float*)(msgB + (size_t)E * 32);
    float*  agg2  = agg1 + (size_t)N * 32;
    float4* erec  = (float4*)(agg2 + (size_t)N * 32);
    int*    start = (int*)(erec + E);
    int*    bsum  = start + 2 * N;
    unsigned short* Wt1 = (unsigned short*)(bsum + 256);
    unsigned short* Wt2 = Wt1 + 320 * 64;
    uint2*  rank  = (uint2*)msgB;    // prep-only, dead before msgB first written

    const dim3 blk(256);
    const int tb   = (N + 31) / 32;
    const int gb   = (N + 63) / 64;
    const int e256 = (E + 255) / 256;
    const int n2k  = (2 * N + 1023) / 1024;   // <=128 (scan3 prefix cap)
    const int itot = 2 * N + 320 * 96;
    int* dstart = start + N;

    // ---- prep (5 launches) ----
    init_kernel<<<(itot + 255) / 256, blk, 0, stream>>>(start, 2 * N, W1, root1, W2, root2, Wt1, Wt2);
    count_rank_kernel<<<e256, blk, 0, stream>>>(ei, start, rank, N, E);
    scan1_kernel<<<n2k, 1024, 0, stream>>>(start, bsum, 2 * N);
    scan3_kernel<<<n2k, 1024, 0, stream>>>(start, bsum, 2 * N);
    scatter_plain_kernel<<<e256, blk, 0, stream>>>(ei, pseudo, start, rank, erec, N, E);

    // ---- layers (4 launches) ----
    layer_tm0<<<tb, blk, 0, stream>>>(x, Wt1, b1, start, erec, agg1, (uint4*)msgA, N, E);
    layer_gtm<1><<<tb, blk, 0, stream>>>(agg1, skip, Wt1, b1, start, dstart, erec,
                                         (const uint4*)msgA, (uint4*)msgB, agg2, N, E);
    layer_gtm<2><<<tb, blk, 0, stream>>>(agg2, nullptr, Wt2, b2, start, dstart, erec,
                                         (const uint4*)msgB, (uint4*)msgA, out, N, E);
    gather_kernel<<<gb, blk, 0, stream>>>(dstart, (const uint4*)msgA, out, N, E);
}

// Round 14
// 245.433 us; speedup vs baseline: 1.7636x; 1.0251x over previous
//
#include <hip/hip_runtime.h>
#include <hip/hip_bf16.h>

// 3-layer SplineConv (3x3, degree 2, open spline). Atomic-free, deep fusion.
// Round 14: ILP round on the round-13 structure (251 us):
//   - M phase: erec[e+64] prefetched before processing edge e (hide global lat)
//   - fused gather (layer_gtm) and final gather: unroll x2, dual accumulators
// TN=32 node tiles: LDS 18.9 KB, grid 1563. Wave w owns row-half (w&1) and
//   col-tile-group (w>>1). Prep: dual counting sort, rank captured in count
//   pass -> atomic-free scatter; packed float4 erec {src,dpos,p0,p1}.

typedef __attribute__((ext_vector_type(8))) short short8;
typedef __attribute__((ext_vector_type(4))) float f32x4;

__device__ __forceinline__ float blo(unsigned u) {
    union { unsigned u; float f; } x; x.u = u << 16; return x.f;
}
__device__ __forceinline__ float bhi(unsigned u) {
    union { unsigned u; float f; } x; x.u = u & 0xffff0000u; return x.f;
}
__device__ __forceinline__ unsigned short f2bf(float f) {
    union { float f; unsigned u; } x; x.f = f;
    unsigned r = x.u + 0x7fffu + ((x.u >> 16) & 1u);   // RNE
    return (unsigned short)(r >> 16);
}
__device__ __forceinline__ short8 cvt8(const float* p) {
    float4 a = *(const float4*)p;
    float4 b = *(const float4*)(p + 4);
    short8 r;
    r[0] = (short)f2bf(a.x); r[1] = (short)f2bf(a.y);
    r[2] = (short)f2bf(a.z); r[3] = (short)f2bf(a.w);
    r[4] = (short)f2bf(b.x); r[5] = (short)f2bf(b.y);
    r[6] = (short)f2bf(b.z); r[7] = (short)f2bf(b.w);
    return r;
}

#define YROW 296   // sY row stride in shorts (592 B, 16B-aligned)

// ---- M phase: msgs for the block's src-CSR segment, y from LDS.
//      Software-pipelined: next erec prefetched before current edge's math. ----
__device__ __forceinline__ void m_phase(const unsigned short* sY,
                                        const int* __restrict__ sstart,
                                        const float4* __restrict__ erec,
                                        uint4* __restrict__ msgOut,
                                        int n0, int t, int N, int E)
{
    const int e0 = sstart[n0];
    const int e1 = (n0 + 32 < N) ? sstart[n0 + 32] : E;
    const int l  = t & 3;

    int e = e0 + (t >> 2);
    if (e >= e1) return;
    float4 r = erec[e];
    while (true) {
        const int en = e + 64;
        float4 rn;
        if (en < e1) rn = erec[en];     // prefetch: latency hides behind LDS+VALU below

        const int srcl = __float_as_int(r.x) - n0;
        const int dp   = __float_as_int(r.y);
        const float p0 = r.z, p1 = r.w;

        const float qb[3] = {0.5f * (1.f - p0) * (1.f - p0), -p0 * p0 + p0 + 0.5f, 0.5f * p0 * p0};
        const float qa[3] = {0.5f * (1.f - p1) * (1.f - p1), -p1 * p1 + p1 + 0.5f, 0.5f * p1 * p1};

        const uint4* yb = (const uint4*)(sY + srcl * YROW) + l;
        float s[8] = {0.f, 0.f, 0.f, 0.f, 0.f, 0.f, 0.f, 0.f};
        #pragma unroll
        for (int a = 0; a < 3; ++a) {
            float z[8] = {0.f, 0.f, 0.f, 0.f, 0.f, 0.f, 0.f, 0.f};
            #pragma unroll
            for (int b = 0; b < 3; ++b) {
                uint4 v = yb[(a * 3 + b) * 4];
                const float cw = qb[b];
                z[0] = fmaf(cw, blo(v.x), z[0]); z[1] = fmaf(cw, bhi(v.x), z[1]);
                z[2] = fmaf(cw, blo(v.y), z[2]); z[3] = fmaf(cw, bhi(v.y), z[3]);
                z[4] = fmaf(cw, blo(v.z), z[4]); z[5] = fmaf(cw, bhi(v.z), z[5]);
                z[6] = fmaf(cw, blo(v.w), z[6]); z[7] = fmaf(cw, bhi(v.w), z[7]);
            }
            #pragma unroll
            for (int j = 0; j < 8; ++j) s[j] = fmaf(qa[a], z[j], s[j]);
        }

        union { uint4 u; __hip_bfloat162 h[4]; } o;
        #pragma unroll
        for (int j = 0; j < 4; ++j)
            o.h[j] = __float22bfloat162_rn(float2{s[2 * j], s[2 * j + 1]});
        msgOut[(size_t)dp * 4 + l] = o.u;

        if (en >= e1) break;
        r = rn; e = en;
    }
}

// ---- T core (TN=32): wave owns row-half rh, col-tile-group cg (10 tiles) ----
template<int NHALF>  // 2: K=64, 1: K=32
__device__ __forceinline__ void t_core(short8 a0, short8 a1,
                                       const unsigned short* __restrict__ Wt,
                                       const float* __restrict__ bias,
                                       unsigned short* sY, float* __restrict__ aggOut,
                                       int n0, int rh, int cg, int lc, int q, int N)
{
    const int CIN = NHALF * 32;
    f32x4 acc[10];
    #pragma unroll
    for (int j = 0; j < 10; ++j) acc[j] = (f32x4){0.f, 0.f, 0.f, 0.f};

    #pragma unroll
    for (int j = 0; j < 10; ++j) {
        const int ti = cg * 10 + j;
        const unsigned short* wp = Wt + ((size_t)(ti * 16 + lc)) * CIN + q * 8;
        acc[j] = __builtin_amdgcn_mfma_f32_16x16x32_bf16(a0, *(const short8*)wp, acc[j], 0, 0, 0);
        if (NHALF == 2)
            acc[j] = __builtin_amdgcn_mfma_f32_16x16x32_bf16(a1, *(const short8*)(wp + 32), acc[j], 0, 0, 0);
    }

    #pragma unroll
    for (int j = 0; j < 10; ++j) {
        const int ti = cg * 10 + j;
        if (ti < 18) {
            #pragma unroll
            for (int r = 0; r < 4; ++r) {
                int nl = rh * 16 + q * 4 + r;
                sY[nl * YROW + ti * 16 + lc] = f2bf(acc[j][r]);
            }
        } else {
            int c = (ti - 18) * 16 + lc;
            float bv = bias[c];
            #pragma unroll
            for (int r = 0; r < 4; ++r) {
                int n = n0 + rh * 16 + q * 4 + r;
                if (n < N) aggOut[(size_t)n * 32 + c] = acc[j][r] + bv;
            }
        }
    }
}

// L1: X = x [N,64] from global
__global__ __launch_bounds__(256)
void layer_tm0(const float* __restrict__ Xa,
               const unsigned short* __restrict__ Wt, const float* __restrict__ bias,
               const int* __restrict__ sstart, const float4* __restrict__ erec,
               float* __restrict__ aggOut, uint4* __restrict__ msgOut, int N, int E)
{
    __shared__ __align__(16) unsigned short sY[32 * YROW];   // 18,944 B
    const int t = threadIdx.x, wv = t >> 6, lane = t & 63;
    const int lc = lane & 15, q = lane >> 4;
    const int rh = wv & 1, cg = wv >> 1;
    const int n0 = blockIdx.x * 32;

    int na = n0 + rh * 16 + lc;
    if (na >= N) na = N - 1;
    const float* p = Xa + (size_t)na * 64 + q * 8;
    short8 a0 = cvt8(p);
    short8 a1 = cvt8(p + 32);

    t_core<2>(a0, a1, Wt, bias, sY, aggOut, n0, rh, cg, lc, q, N);
    __syncthreads();
    m_phase(sY, sstart, erec, msgOut, n0, t, N, E);
}

// L2 (MODE 1): X = [relu(aggPrev + gather msgIn) | skip]; L3 (MODE 2): X = relu(...)
template<int MODE>
__global__ __launch_bounds__(256)
void layer_gtm(const float* __restrict__ aggPrev, const float* __restrict__ skipv,
               const unsigned short* __restrict__ Wt, const float* __restrict__ bias,
               const int* __restrict__ sstart, const int* __restrict__ dstart,
               const float4* __restrict__ erec,
               const uint4* __restrict__ msgIn, uint4* __restrict__ msgOut,
               float* __restrict__ aggOut, int N, int E)
{
    __shared__ __align__(16) unsigned short sY[32 * YROW];
    const int t = threadIdx.x, wv = t >> 6, lane = t & 63;
    const int lc = lane & 15, q = lane >> 4;
    const int rh = wv & 1, cg = wv >> 1;
    const int n0 = blockIdx.x * 32;

    int na = n0 + rh * 16 + lc;
    if (na >= N) na = N - 1;

    // fused gather: this lane's 8 channels (q*8..q*8+7) of node na; unroll x2
    const float* ap = aggPrev + (size_t)na * 32 + q * 8;
    float4 r0 = *(const float4*)ap;
    float4 r1 = *(const float4*)(ap + 4);
    float h[8] = {r0.x, r0.y, r0.z, r0.w, r1.x, r1.y, r1.z, r1.w};
    float g[8] = {0.f, 0.f, 0.f, 0.f, 0.f, 0.f, 0.f, 0.f};
    const int ge0 = dstart[na] - E;
    const int ge1 = ((na + 1 < N) ? dstart[na + 1] : 2 * E) - E;
    int e = ge0;
    for (; e + 2 <= ge1; e += 2) {
        uint4 v0 = msgIn[(size_t)e * 4 + q];
        uint4 v1 = msgIn[(size_t)(e + 1) * 4 + q];
        h[0] += blo(v0.x); h[1] += bhi(v0.x); h[2] += blo(v0.y); h[3] += bhi(v0.y);
        h[4] += blo(v0.z); h[5] += bhi(v0.z); h[6] += blo(v0.w); h[7] += bhi(v0.w);
        g[0] += blo(v1.x); g[1] += bhi(v1.x); g[2] += blo(v1.y); g[3] += bhi(v1.y);
        g[4] += blo(v1.z); g[5] += bhi(v1.z); g[6] += blo(v1.w); g[7] += bhi(v1.w);
    }
    if (e < ge1) {
        uint4 v = msgIn[(size_t)e * 4 + q];
        h[0] += blo(v.x); h[1] += bhi(v.x); h[2] += blo(v.y); h[3] += bhi(v.y);
        h[4] += blo(v.z); h[5] += bhi(v.z); h[6] += blo(v.w); h[7] += bhi(v.w);
    }
    #pragma unroll
    for (int j = 0; j < 8; ++j) h[j] += g[j];

    union { short8 v; __hip_bfloat162 h2[4]; } pk;
    #pragma unroll
    for (int j = 0; j < 4; ++j)
        pk.h2[j] = __float22bfloat162_rn(float2{fmaxf(h[2 * j], 0.f), fmaxf(h[2 * j + 1], 0.f)});
    short8 a0 = pk.v;
    short8 a1;
    if (MODE == 1) a1 = cvt8(skipv + (size_t)na * 32 + q * 8);

    t_core<(MODE == 1) ? 2 : 1>(a0, a1, Wt, bias, sY, aggOut, n0, rh, cg, lc, q, N);
    __syncthreads();
    m_phase(sY, sstart, erec, msgOut, n0, t, N, E);
}

// final gather: out = relu(out + sum msg rows); unroll x2, dual accumulators
__global__ __launch_bounds__(256)
void gather_kernel(const int* __restrict__ dstart, const uint4* __restrict__ msg4,
                   float* __restrict__ agg, int N, int E)
{
    const int t = threadIdx.x;
    const int n = blockIdx.x * 64 + (t >> 2);
    if (n >= N) return;
    const int l = t & 3;

    const int e0 = dstart[n] - E;
    const int e1 = ((n + 1 < N) ? dstart[n + 1] : 2 * E) - E;

    float4* ap = (float4*)(agg + (size_t)n * 32 + l * 8);
    float4 A = ap[0], B = ap[1];
    float4 C = {0.f, 0.f, 0.f, 0.f}, D = {0.f, 0.f, 0.f, 0.f};
    const uint4* mp = msg4 + l;
    int e = e0;
    for (; e + 2 <= e1; e += 2) {
        uint4 v0 = mp[(size_t)e * 4];
        uint4 v1 = mp[(size_t)(e + 1) * 4];
        A.x += blo(v0.x); A.y += bhi(v0.x); A.z += blo(v0.y); A.w += bhi(v0.y);
        B.x += blo(v0.z); B.y += bhi(v0.z); B.z += blo(v0.w); B.w += bhi(v0.w);
        C.x += blo(v1.x); C.y += bhi(v1.x); C.z += blo(v1.y); C.w += bhi(v1.y);
        D.x += blo(v1.z); D.y += bhi(v1.z); D.z += blo(v1.w); D.w += bhi(v1.w);
    }
    if (e < e1) {
        uint4 v = mp[(size_t)e * 4];
        A.x += blo(v.x); A.y += bhi(v.x); A.z += blo(v.y); A.w += bhi(v.y);
        B.x += blo(v.z); B.y += bhi(v.z); B.z += blo(v.w); B.w += bhi(v.w);
    }
    A.x += C.x; A.y += C.y; A.z += C.z; A.w += C.w;
    B.x += D.x; B.y += D.y; B.z += D.z; B.w += D.w;
    A.x = fmaxf(A.x, 0.f); A.y = fmaxf(A.y, 0.f); A.z = fmaxf(A.z, 0.f); A.w = fmaxf(A.w, 0.f);
    B.x = fmaxf(B.x, 0.f); B.y = fmaxf(B.y, 0.f); B.z = fmaxf(B.z, 0.f); B.w = fmaxf(B.w, 0.f);
    ap[0] = A; ap[1] = B;
}

// ---------- prep ----------

__global__ __launch_bounds__(256)
void init_kernel(int* __restrict__ hist, int n2,
                 const float* __restrict__ W1, const float* __restrict__ root1,
                 const float* __restrict__ W2, const float* __restrict__ root2,
                 unsigned short* __restrict__ Wt1, unsigned short* __restrict__ Wt2)
{
    int i = blockIdx.x * 256 + threadIdx.x;
    if (i < n2) { hist[i] = 0; return; }
    int j = i - n2;
    if (j < 320 * 64) {
        int col = j / 64, k = j % 64;
        float v = (col < 288) ? W1[((size_t)(col >> 5) * 64 + k) * 32 + (col & 31)]
                              : root1[(size_t)k * 32 + (col - 288)];
        Wt1[j] = f2bf(v);
    } else if (j < 320 * 96) {
        int jj = j - 320 * 64;
        int col = jj / 32, k = jj % 32;
        float v = (col < 288) ? W2[((size_t)(col >> 5) * 32 + k) * 32 + (col & 31)]
                              : root2[(size_t)k * 32 + (col - 288)];
        Wt2[jj] = f2bf(v);
    }
}

__global__ __launch_bounds__(256)
void count_rank_kernel(const int* __restrict__ ei, int* __restrict__ hist,
                       uint2* __restrict__ rank, int N, int E)
{
    int e = blockIdx.x * 256 + threadIdx.x;
    if (e >= E) return;
    unsigned rs = atomicAdd(&hist[ei[e]], 1);
    unsigned rd = atomicAdd(&hist[N + ei[E + e]], 1);
    rank[e] = uint2{rs, rd};
}

__global__ __launch_bounds__(1024)
void scan1_kernel(int* __restrict__ hist, int* __restrict__ bsum, int n)
{
    __shared__ int s[1024];
    int tid = threadIdx.x;
    int i = blockIdx.x * 1024 + tid;
    int v = (i < n) ? hist[i] : 0;
    s[tid] = v;
    __syncthreads();
    for (int off = 1; off < 1024; off <<= 1) {
        int add = (tid >= off) ? s[tid - off] : 0;
        __syncthreads();
        s[tid] += add;
        __syncthreads();
    }
    if (i < n) hist[i] = s[tid] - v;
    if (tid == 1023) bsum[blockIdx.x] = s[1023];
}

__global__ __launch_bounds__(1024)
void scan3_kernel(int* __restrict__ hist, const int* __restrict__ bsum, int n)
{
    __shared__ int sred[128];
    int tid = threadIdx.x;
    int b = blockIdx.x;
    if (tid < 128) sred[tid] = (tid < b) ? bsum[tid] : 0;
    __syncthreads();
    for (int off = 64; off > 0; off >>= 1) {
        if (tid < off) sred[tid] += sred[tid + off];
        __syncthreads();
    }
    int pre = sred[0];
    int i = b * 1024 + tid;
    if (i < n) hist[i] += pre;
}

__global__ __launch_bounds__(256)
void scatter_plain_kernel(const int* __restrict__ ei, const float* __restrict__ pseudo,
                          const int* __restrict__ start, const uint2* __restrict__ rank,
                          float4* __restrict__ erec, int N, int E)
{
    int e = blockIdx.x * 256 + threadIdx.x;
    if (e >= E) return;
    int sv = ei[e];
    int dv = ei[E + e];
    uint2 rk = rank[e];
    int ps = start[sv] + (int)rk.x;
    int pd = start[N + dv] + (int)rk.y - E;
    float4 r;
    r.x = __int_as_float(sv);
    r.y = __int_as_float(pd);
    r.z = pseudo[2 * (size_t)e];
    r.w = pseudo[2 * (size_t)e + 1];
    erec[ps] = r;
}

extern "C" void kernel_launch(void* const* d_in, const int* in_sizes, int n_in,
                              void* d_out, int out_size, void* d_ws, size_t ws_size,
                              hipStream_t stream) {
    const float* x      = (const float*)d_in[0];
    const int*   ei     = (const int*)  d_in[1];
    const float* pseudo = (const float*)d_in[2];
    const float* skip   = (const float*)d_in[3];
    const float* W1     = (const float*)d_in[4];
    const float* root1  = (const float*)d_in[5];
    const float* b1     = (const float*)d_in[6];
    const float* W2     = (const float*)d_in[7];
    const float* root2  = (const float*)d_in[8];
    const float* b2     = (const float*)d_in[9];

    const int N = in_sizes[0] / 64;
    const int E = in_sizes[1] / 2;
    float* out = (float*)d_out;

    // ws (~71 MB): msgA[E*32 bf16] msgB[E*32 bf16] agg1[N*32] agg2[N*32]
    //              erec[E f4] start[2N] bsum[256] Wt1 Wt2; rank aliases msgB
    unsigned short* msgA = (unsigned short*)d_ws;
    unsigned short* msgB = msgA + (size_t)E * 32;
    float*  agg1  = (float*)(msgB + (size_t)E * 32);
    float*  agg2  = agg1 + (size_t)N * 32;
    float4* erec  = (float4*)(agg2 + (size_t)N * 32);
    int*    start = (int*)(erec + E);
    int*    bsum  = start + 2 * N;
    unsigned short* Wt1 = (unsigned short*)(bsum + 256);
    unsigned short* Wt2 = Wt1 + 320 * 64;
    uint2*  rank  = (uint2*)msgB;    // prep-only, dead before msgB first written

    const dim3 blk(256);
    const int tb   = (N + 31) / 32;
    const int gb   = (N + 63) / 64;
    const int e256 = (E + 255) / 256;
    const int n2k  = (2 * N + 1023) / 1024;   // <=128 (scan3 prefix cap)
    const int itot = 2 * N + 320 * 96;
    int* dstart = start + N;

    // ---- prep (5 launches) ----
    init_kernel<<<(itot + 255) / 256, blk, 0, stream>>>(start, 2 * N, W1, root1, W2, root2, Wt1, Wt2);
    count_rank_kernel<<<e256, blk, 0, stream>>>(ei, start, rank, N, E);
    scan1_kernel<<<n2k, 1024, 0, stream>>>(start, bsum, 2 * N);
    scan3_kernel<<<n2k, 1024, 0, stream>>>(start, bsum, 2 * N);
    scatter_plain_kernel<<<e256, blk, 0, stream>>>(ei, pseudo, start, rank, erec, N, E);

    // ---- layers (4 launches) ----
    layer_tm0<<<tb, blk, 0, stream>>>(x, Wt1, b1, start, erec, agg1, (uint4*)msgA, N, E);
    layer_gtm<1><<<tb, blk, 0, stream>>>(agg1, skip, Wt1, b1, start, dstart, erec,
                                         (const uint4*)msgA, (uint4*)msgB, agg2, N, E);
    layer_gtm<2><<<tb, blk, 0, stream>>>(agg2, nullptr, Wt2, b2, start, dstart, erec,
                                         (const uint4*)msgB, (uint4*)msgA, out, N, E);
    gather_kernel<<<gb, blk, 0, stream>>>(dstart, (const uint4*)msgA, out, N, E);
}

// Round 15
// 231.379 us; speedup vs baseline: 1.8707x; 1.0607x over previous
//
#include <hip/hip_runtime.h>
#include <hip/hip_bf16.h>

// 3-layer SplineConv (3x3, degree 2, open spline). Atomic-free, deep fusion.
// Round 15: VGPR-cliff round. Round-14 layer kernels sat at 68 VGPRs -- just
//   over the 64-reg occupancy cliff (waves/SIMD halve at 64/128/256), capping
//   residency at 4 blocks/CU though LDS allows 8. t_core now computes each
//   col-tile's accumulator and writes it IMMEDIATELY (live accs 40 -> ~8);
//   __launch_bounds__(256,8) pins 8 waves/EU (=8 blocks/CU).
// Structure otherwise identical to round 14 (245 us): TN=32 tiles, fused
//   gather->transform->msg per layer, m_phase erec prefetch, dual counting
//   sort with rank capture -> atomic-free scatter.

typedef __attribute__((ext_vector_type(8))) short short8;
typedef __attribute__((ext_vector_type(4))) float f32x4;

__device__ __forceinline__ float blo(unsigned u) {
    union { unsigned u; float f; } x; x.u = u << 16; return x.f;
}
__device__ __forceinline__ float bhi(unsigned u) {
    union { unsigned u; float f; } x; x.u = u & 0xffff0000u; return x.f;
}
__device__ __forceinline__ unsigned short f2bf(float f) {
    union { float f; unsigned u; } x; x.f = f;
    unsigned r = x.u + 0x7fffu + ((x.u >> 16) & 1u);   // RNE
    return (unsigned short)(r >> 16);
}
__device__ __forceinline__ short8 cvt8(const float* p) {
    float4 a = *(const float4*)p;
    float4 b = *(const float4*)(p + 4);
    short8 r;
    r[0] = (short)f2bf(a.x); r[1] = (short)f2bf(a.y);
    r[2] = (short)f2bf(a.z); r[3] = (short)f2bf(a.w);
    r[4] = (short)f2bf(b.x); r[5] = (short)f2bf(b.y);
    r[6] = (short)f2bf(b.z); r[7] = (short)f2bf(b.w);
    return r;
}

#define YROW 296   // sY row stride in shorts (592 B, 16B-aligned)

// ---- M phase: msgs for the block's src-CSR segment, y from LDS.
//      Software-pipelined: next erec prefetched before current edge's math. ----
__device__ __forceinline__ void m_phase(const unsigned short* sY,
                                        const int* __restrict__ sstart,
                                        const float4* __restrict__ erec,
                                        uint4* __restrict__ msgOut,
                                        int n0, int t, int N, int E)
{
    const int e0 = sstart[n0];
    const int e1 = (n0 + 32 < N) ? sstart[n0 + 32] : E;
    const int l  = t & 3;

    int e = e0 + (t >> 2);
    if (e >= e1) return;
    float4 r = erec[e];
    while (true) {
        const int en = e + 64;
        float4 rn;
        if (en < e1) rn = erec[en];     // prefetch: latency hides behind LDS+VALU below

        const int srcl = __float_as_int(r.x) - n0;
        const int dp   = __float_as_int(r.y);
        const float p0 = r.z, p1 = r.w;

        const float qb[3] = {0.5f * (1.f - p0) * (1.f - p0), -p0 * p0 + p0 + 0.5f, 0.5f * p0 * p0};
        const float qa[3] = {0.5f * (1.f - p1) * (1.f - p1), -p1 * p1 + p1 + 0.5f, 0.5f * p1 * p1};

        const uint4* yb = (const uint4*)(sY + srcl * YROW) + l;
        float s[8] = {0.f, 0.f, 0.f, 0.f, 0.f, 0.f, 0.f, 0.f};
        #pragma unroll
        for (int a = 0; a < 3; ++a) {
            float z[8] = {0.f, 0.f, 0.f, 0.f, 0.f, 0.f, 0.f, 0.f};
            #pragma unroll
            for (int b = 0; b < 3; ++b) {
                uint4 v = yb[(a * 3 + b) * 4];
                const float cw = qb[b];
                z[0] = fmaf(cw, blo(v.x), z[0]); z[1] = fmaf(cw, bhi(v.x), z[1]);
                z[2] = fmaf(cw, blo(v.y), z[2]); z[3] = fmaf(cw, bhi(v.y), z[3]);
                z[4] = fmaf(cw, blo(v.z), z[4]); z[5] = fmaf(cw, bhi(v.z), z[5]);
                z[6] = fmaf(cw, blo(v.w), z[6]); z[7] = fmaf(cw, bhi(v.w), z[7]);
            }
            #pragma unroll
            for (int j = 0; j < 8; ++j) s[j] = fmaf(qa[a], z[j], s[j]);
        }

        union { uint4 u; __hip_bfloat162 h[4]; } o;
        #pragma unroll
        for (int j = 0; j < 4; ++j)
            o.h[j] = __float22bfloat162_rn(float2{s[2 * j], s[2 * j + 1]});
        msgOut[(size_t)dp * 4 + l] = o.u;

        if (en >= e1) break;
        r = rn; e = en;
    }
}

// ---- T core (TN=32): wave owns row-half rh, col-tile-group cg (10 tiles).
//      Per-tile acc, written immediately -> ~8 live acc VGPRs (was 40). ----
template<int NHALF>  // 2: K=64, 1: K=32
__device__ __forceinline__ void t_core(short8 a0, short8 a1,
                                       const unsigned short* __restrict__ Wt,
                                       const float* __restrict__ bias,
                                       unsigned short* sY, float* __restrict__ aggOut,
                                       int n0, int rh, int cg, int lc, int q, int N)
{
    const int CIN = NHALF * 32;
    #pragma unroll
    for (int j = 0; j < 10; ++j) {
        const int ti = cg * 10 + j;
        const unsigned short* wp = Wt + ((size_t)(ti * 16 + lc)) * CIN + q * 8;
        f32x4 acc = (f32x4){0.f, 0.f, 0.f, 0.f};
        acc = __builtin_amdgcn_mfma_f32_16x16x32_bf16(a0, *(const short8*)wp, acc, 0, 0, 0);
        if (NHALF == 2)
            acc = __builtin_amdgcn_mfma_f32_16x16x32_bf16(a1, *(const short8*)(wp + 32), acc, 0, 0, 0);

        if (ti < 18) {
            #pragma unroll
            for (int r = 0; r < 4; ++r) {
                int nl = rh * 16 + q * 4 + r;
                sY[nl * YROW + ti * 16 + lc] = f2bf(acc[r]);
            }
        } else {
            int c = (ti - 18) * 16 + lc;
            float bv = bias[c];
            #pragma unroll
            for (int r = 0; r < 4; ++r) {
                int n = n0 + rh * 16 + q * 4 + r;
                if (n < N) aggOut[(size_t)n * 32 + c] = acc[r] + bv;
            }
        }
    }
}

// L1: X = x [N,64] from global
__global__ __launch_bounds__(256, 8)
void layer_tm0(const float* __restrict__ Xa,
               const unsigned short* __restrict__ Wt, const float* __restrict__ bias,
               const int* __restrict__ sstart, const float4* __restrict__ erec,
               float* __restrict__ aggOut, uint4* __restrict__ msgOut, int N, int E)
{
    __shared__ __align__(16) unsigned short sY[32 * YROW];   // 18,944 B
    const int t = threadIdx.x, wv = t >> 6, lane = t & 63;
    const int lc = lane & 15, q = lane >> 4;
    const int rh = wv & 1, cg = wv >> 1;
    const int n0 = blockIdx.x * 32;

    int na = n0 + rh * 16 + lc;
    if (na >= N) na = N - 1;
    const float* p = Xa + (size_t)na * 64 + q * 8;
    short8 a0 = cvt8(p);
    short8 a1 = cvt8(p + 32);

    t_core<2>(a0, a1, Wt, bias, sY, aggOut, n0, rh, cg, lc, q, N);
    __syncthreads();
    m_phase(sY, sstart, erec, msgOut, n0, t, N, E);
}

// L2 (MODE 1): X = [relu(aggPrev + gather msgIn) | skip]; L3 (MODE 2): X = relu(...)
template<int MODE>
__global__ __launch_bounds__(256, 8)
void layer_gtm(const float* __restrict__ aggPrev, const float* __restrict__ skipv,
               const unsigned short* __restrict__ Wt, const float* __restrict__ bias,
               const int* __restrict__ sstart, const int* __restrict__ dstart,
               const float4* __restrict__ erec,
               const uint4* __restrict__ msgIn, uint4* __restrict__ msgOut,
               float* __restrict__ aggOut, int N, int E)
{
    __shared__ __align__(16) unsigned short sY[32 * YROW];
    const int t = threadIdx.x, wv = t >> 6, lane = t & 63;
    const int lc = lane & 15, q = lane >> 4;
    const int rh = wv & 1, cg = wv >> 1;
    const int n0 = blockIdx.x * 32;

    int na = n0 + rh * 16 + lc;
    if (na >= N) na = N - 1;

    // fused gather: this lane's 8 channels (q*8..q*8+7) of node na; unroll x2
    const float* ap = aggPrev + (size_t)na * 32 + q * 8;
    float4 r0 = *(const float4*)ap;
    float4 r1 = *(const float4*)(ap + 4);
    float h[8] = {r0.x, r0.y, r0.z, r0.w, r1.x, r1.y, r1.z, r1.w};
    float g[8] = {0.f, 0.f, 0.f, 0.f, 0.f, 0.f, 0.f, 0.f};
    const int ge0 = dstart[na] - E;
    const int ge1 = ((na + 1 < N) ? dstart[na + 1] : 2 * E) - E;
    int e = ge0;
    for (; e + 2 <= ge1; e += 2) {
        uint4 v0 = msgIn[(size_t)e * 4 + q];
        uint4 v1 = msgIn[(size_t)(e + 1) * 4 + q];
        h[0] += blo(v0.x); h[1] += bhi(v0.x); h[2] += blo(v0.y); h[3] += bhi(v0.y);
        h[4] += blo(v0.z); h[5] += bhi(v0.z); h[6] += blo(v0.w); h[7] += bhi(v0.w);
        g[0] += blo(v1.x); g[1] += bhi(v1.x); g[2] += blo(v1.y); g[3] += bhi(v1.y);
        g[4] += blo(v1.z); g[5] += bhi(v1.z); g[6] += blo(v1.w); g[7] += bhi(v1.w);
    }
    if (e < ge1) {
        uint4 v = msgIn[(size_t)e * 4 + q];
        h[0] += blo(v.x); h[1] += bhi(v.x); h[2] += blo(v.y); h[3] += bhi(v.y);
        h[4] += blo(v.z); h[5] += bhi(v.z); h[6] += blo(v.w); h[7] += bhi(v.w);
    }
    #pragma unroll
    for (int j = 0; j < 8; ++j) h[j] += g[j];

    union { short8 v; __hip_bfloat162 h2[4]; } pk;
    #pragma unroll
    for (int j = 0; j < 4; ++j)
        pk.h2[j] = __float22bfloat162_rn(float2{fmaxf(h[2 * j], 0.f), fmaxf(h[2 * j + 1], 0.f)});
    short8 a0 = pk.v;
    short8 a1;
    if (MODE == 1) a1 = cvt8(skipv + (size_t)na * 32 + q * 8);

    t_core<(MODE == 1) ? 2 : 1>(a0, a1, Wt, bias, sY, aggOut, n0, rh, cg, lc, q, N);
    __syncthreads();
    m_phase(sY, sstart, erec, msgOut, n0, t, N, E);
}

// final gather: out = relu(out + sum msg rows); unroll x2, dual accumulators
__global__ __launch_bounds__(256)
void gather_kernel(const int* __restrict__ dstart, const uint4* __restrict__ msg4,
                   float* __restrict__ agg, int N, int E)
{
    const int t = threadIdx.x;
    const int n = blockIdx.x * 64 + (t >> 2);
    if (n >= N) return;
    const int l = t & 3;

    const int e0 = dstart[n] - E;
    const int e1 = ((n + 1 < N) ? dstart[n + 1] : 2 * E) - E;

    float4* ap = (float4*)(agg + (size_t)n * 32 + l * 8);
    float4 A = ap[0], B = ap[1];
    float4 C = {0.f, 0.f, 0.f, 0.f}, D = {0.f, 0.f, 0.f, 0.f};
    const uint4* mp = msg4 + l;
    int e = e0;
    for (; e + 2 <= e1; e += 2) {
        uint4 v0 = mp[(size_t)e * 4];
        uint4 v1 = mp[(size_t)(e + 1) * 4];
        A.x += blo(v0.x); A.y += bhi(v0.x); A.z += blo(v0.y); A.w += bhi(v0.y);
        B.x += blo(v0.z); B.y += bhi(v0.z); B.z += blo(v0.w); B.w += bhi(v0.w);
        C.x += blo(v1.x); C.y += bhi(v1.x); C.z += blo(v1.y); C.w += bhi(v1.y);
        D.x += blo(v1.z); D.y += bhi(v1.z); D.z += blo(v1.w); D.w += bhi(v1.w);
    }
    if (e < e1) {
        uint4 v = mp[(size_t)e * 4];
        A.x += blo(v.x); A.y += bhi(v.x); A.z += blo(v.y); A.w += bhi(v.y);
        B.x += blo(v.z); B.y += bhi(v.z); B.z += blo(v.w); B.w += bhi(v.w);
    }
    A.x += C.x; A.y += C.y; A.z += C.z; A.w += C.w;
    B.x += D.x; B.y += D.y; B.z += D.z; B.w += D.w;
    A.x = fmaxf(A.x, 0.f); A.y = fmaxf(A.y, 0.f); A.z = fmaxf(A.z, 0.f); A.w = fmaxf(A.w, 0.f);
    B.x = fmaxf(B.x, 0.f); B.y = fmaxf(B.y, 0.f); B.z = fmaxf(B.z, 0.f); B.w = fmaxf(B.w, 0.f);
    ap[0] = A; ap[1] = B;
}

// ---------- prep ----------

__global__ __launch_bounds__(256)
void init_kernel(int* __restrict__ hist, int n2,
                 const float* __restrict__ W1, const float* __restrict__ root1,
                 const float* __restrict__ W2, const float* __restrict__ root2,
                 unsigned short* __restrict__ Wt1, unsigned short* __restrict__ Wt2)
{
    int i = blockIdx.x * 256 + threadIdx.x;
    if (i < n2) { hist[i] = 0; return; }
    int j = i - n2;
    if (j < 320 * 64) {
        int col = j / 64, k = j % 64;
        float v = (col < 288) ? W1[((size_t)(col >> 5) * 64 + k) * 32 + (col & 31)]
                              : root1[(size_t)k * 32 + (col - 288)];
        Wt1[j] = f2bf(v);
    } else if (j < 320 * 96) {
        int jj = j - 320 * 64;
        int col = jj / 32, k = jj % 32;
        float v = (col < 288) ? W2[((size_t)(col >> 5) * 32 + k) * 32 + (col & 31)]
                              : root2[(size_t)k * 32 + (col - 288)];
        Wt2[jj] = f2bf(v);
    }
}

__global__ __launch_bounds__(256)
void count_rank_kernel(const int* __restrict__ ei, int* __restrict__ hist,
                       uint2* __restrict__ rank, int N, int E)
{
    int e = blockIdx.x * 256 + threadIdx.x;
    if (e >= E) return;
    unsigned rs = atomicAdd(&hist[ei[e]], 1);
    unsigned rd = atomicAdd(&hist[N + ei[E + e]], 1);
    rank[e] = uint2{rs, rd};
}

__global__ __launch_bounds__(1024)
void scan1_kernel(int* __restrict__ hist, int* __restrict__ bsum, int n)
{
    __shared__ int s[1024];
    int tid = threadIdx.x;
    int i = blockIdx.x * 1024 + tid;
    int v = (i < n) ? hist[i] : 0;
    s[tid] = v;
    __syncthreads();
    for (int off = 1; off < 1024; off <<= 1) {
        int add = (tid >= off) ? s[tid - off] : 0;
        __syncthreads();
        s[tid] += add;
        __syncthreads();
    }
    if (i < n) hist[i] = s[tid] - v;
    if (tid == 1023) bsum[blockIdx.x] = s[1023];
}

__global__ __launch_bounds__(1024)
void scan3_kernel(int* __restrict__ hist, const int* __restrict__ bsum, int n)
{
    __shared__ int sred[128];
    int tid = threadIdx.x;
    int b = blockIdx.x;
    if (tid < 128) sred[tid] = (tid < b) ? bsum[tid] : 0;
    __syncthreads();
    for (int off = 64; off > 0; off >>= 1) {
        if (tid < off) sred[tid] += sred[tid + off];
        __syncthreads();
    }
    int pre = sred[0];
    int i = b * 1024 + tid;
    if (i < n) hist[i] += pre;
}

__global__ __launch_bounds__(256)
void scatter_plain_kernel(const int* __restrict__ ei, const float* __restrict__ pseudo,
                          const int* __restrict__ start, const uint2* __restrict__ rank,
                          float4* __restrict__ erec, int N, int E)
{
    int e = blockIdx.x * 256 + threadIdx.x;
    if (e >= E) return;
    int sv = ei[e];
    int dv = ei[E + e];
    uint2 rk = rank[e];
    int ps = start[sv] + (int)rk.x;
    int pd = start[N + dv] + (int)rk.y - E;
    float4 r;
    r.x = __int_as_float(sv);
    r.y = __int_as_float(pd);
    r.z = pseudo[2 * (size_t)e];
    r.w = pseudo[2 * (size_t)e + 1];
    erec[ps] = r;
}

extern "C" void kernel_launch(void* const* d_in, const int* in_sizes, int n_in,
                              void* d_out, int out_size, void* d_ws, size_t ws_size,
                              hipStream_t stream) {
    const float* x      = (const float*)d_in[0];
    const int*   ei     = (const int*)  d_in[1];
    const float* pseudo = (const float*)d_in[2];
    const float* skip   = (const float*)d_in[3];
    const float* W1     = (const float*)d_in[4];
    const float* root1  = (const float*)d_in[5];
    const float* b1     = (const float*)d_in[6];
    const float* W2     = (const float*)d_in[7];
    const float* root2  = (const float*)d_in[8];
    const float* b2     = (const float*)d_in[9];

    const int N = in_sizes[0] / 64;
    const int E = in_sizes[1] / 2;
    float* out = (float*)d_out;

    // ws (~71 MB): msgA[E*32 bf16] msgB[E*32 bf16] agg1[N*32] agg2[N*32]
    //              erec[E f4] start[2N] bsum[256] Wt1 Wt2; rank aliases msgB
    unsigned short* msgA = (unsigned short*)d_ws;
    unsigned short* msgB = msgA + (size_t)E * 32;
    float*  agg1  = (float*)(msgB + (size_t)E * 32);
    float*  agg2  = agg1 + (size_t)N * 32;
    float4* erec  = (float4*)(agg2 + (size_t)N * 32);
    int*    start = (int*)(erec + E);
    int*    bsum  = start + 2 * N;
    unsigned short* Wt1 = (unsigned short*)(bsum + 256);
    unsigned short* Wt2 = Wt1 + 320 * 64;
    uint2*  rank  = (uint2*)msgB;    // prep-only, dead before msgB first written

    const dim3 blk(256);
    const int tb   = (N + 31) / 32;
    const int gb   = (N + 63) / 64;
    const int e256 = (E + 255) / 256;
    const int n2k  = (2 * N + 1023) / 1024;   // <=128 (scan3 prefix cap)
    const int itot = 2 * N + 320 * 96;
    int* dstart = start + N;

    // ---- prep (5 launches) ----
    init_kernel<<<(itot + 255) / 256, blk, 0, stream>>>(start, 2 * N, W1, root1, W2, root2, Wt1, Wt2);
    count_rank_kernel<<<e256, blk, 0, stream>>>(ei, start, rank, N, E);
    scan1_kernel<<<n2k, 1024, 0, stream>>>(start, bsum, 2 * N);
    scan3_kernel<<<n2k, 1024, 0, stream>>>(start, bsum, 2 * N);
    scatter_plain_kernel<<<e256, blk, 0, stream>>>(ei, pseudo, start, rank, erec, N, E);

    // ---- layers (4 launches) ----
    layer_tm0<<<tb, blk, 0, stream>>>(x, Wt1, b1, start, erec, agg1, (uint4*)msgA, N, E);
    layer_gtm<1><<<tb, blk, 0, stream>>>(agg1, skip, Wt1, b1, start, dstart, erec,
                                         (const uint4*)msgA, (uint4*)msgB, agg2, N, E);
    layer_gtm<2><<<tb, blk, 0, stream>>>(agg2, nullptr, Wt2, b2, start, dstart, erec,
                                         (const uint4*)msgB, (uint4*)msgA, out, N, E);
    gather_kernel<<<gb, blk, 0, stream>>>(dstart, (const uint4*)msgA, out, N, E);
}